// Round 2
// baseline (841.327 us; speedup 1.0000x reference)
//
#include <hip/hip_runtime.h>
#include <stdint.h>

typedef unsigned short u16;
typedef unsigned int   u32;
typedef unsigned long long u64;

typedef __bf16 bf16x8 __attribute__((ext_vector_type(8)));
typedef u16    u16x8  __attribute__((ext_vector_type(8)));
typedef u16    u16x4  __attribute__((ext_vector_type(4)));
typedef float  f32x4  __attribute__((ext_vector_type(4)));

#define BQ 4
#define TT 2048
#define CC 1024
#define HH 16
#define DD 64
#define FF 4096
#define BT 8192      // B*T rows
#define NCH 32       // chunks per sequence
#define LCH 64       // chunk length
#define LS 72        // padded LDS stride for 64-wide tiles (144B, 16B-aligned)

__device__ __forceinline__ float b2f(u16 v) {
  u32 u = ((u32)v) << 16;
  return __builtin_bit_cast(float, u);
}
__device__ __forceinline__ u16 f2b(float f) {
  u32 u = __builtin_bit_cast(u32, f);
  u32 r = (u + 0x7fffu + ((u >> 16) & 1u)) >> 16;   // RNE
  return (u16)r;
}
__device__ __forceinline__ bf16x8 ld8(const u16* p) {
  return __builtin_bit_cast(bf16x8, *(const u16x8*)p);
}
__device__ __forceinline__ float sigmoidf_(float x) {
  return 1.0f / (1.0f + __expf(-x));
}

#define MFMA16(a, b, c) __builtin_amdgcn_mfma_f32_16x16x32_bf16(a, b, c, 0, 0, 0)

// ---------------------------------------------------------------------------
// dtype probe: even-indexed u16s of x. fp32 buffer -> those are low mantissa
// halves (junk exponents, ~9% "plausible"); bf16 buffer -> ~100% plausible.
// flag = 1 means "inputs are bf16".
// ---------------------------------------------------------------------------
__global__ __launch_bounds__(256) void detect_k(const u16* __restrict__ xr,
                                                int* __restrict__ flag)
{
  __shared__ int cnt[4];
  const int tid = threadIdx.x;
  int c = 0;
  for (int i = tid; i < 4096; i += 256) {
    u16 u = xr[2 * i];
    int e = (u >> 7) & 0xFF;
    if (e >= 0x70 && e <= 0x86) ++c;
  }
#pragma unroll
  for (int m = 1; m < 64; m <<= 1) c += __shfl_xor(c, m, 64);
  if ((tid & 63) == 0) cnt[tid >> 6] = c;
  __syncthreads();
  if (tid == 0) *flag = (cnt[0] + cnt[1] + cnt[2] + cnt[3] >= 2048) ? 1 : 0;
}

// canonicalize all tensors to bf16 in ws (cast if fp32, copy if bf16)
struct Cvt { const void* src; u16* dst; u32 n; u32 pad; };
struct CvtArgs { Cvt d[13]; };

__global__ __launch_bounds__(256) void convert_k(CvtArgs a, const int* __restrict__ flag)
{
  const Cvt c = a.d[blockIdx.y];
  u64 i = ((u64)blockIdx.x * 256 + threadIdx.x) * 8;
  if (i >= c.n) return;
  if (*flag) {
    *(u16x8*)(c.dst + i) = *(const u16x8*)((const u16*)c.src + i);
  } else {
    const float* s = (const float*)c.src;
    u16x8 o;
#pragma unroll
    for (int e = 0; e < 8; ++e) o[e] = f2b(s[i + e]);
    *(u16x8*)(c.dst + i) = o;
  }
}

// ---------------------------------------------------------------------------
// Generic bf16 bt-GEMM: C[M,N] = A[M,K] * Bw[N,K]^T
// MODE 0: bf16 out. MODE 1: bf16 out + bf16 residual.
// MODE 2: final out: +residual, store fp32 or bf16 per *flag.
// 128x128 tile, BK=32, manual reg->LDS staging (correctness-first round).
// ---------------------------------------------------------------------------
template <int MODE>
__global__ __launch_bounds__(256) void gemm_bt(
    const u16* __restrict__ A, const u16* __restrict__ Bw,
    void* __restrict__ Cv, const u16* __restrict__ res,
    int M, int N, int K, const int* __restrict__ flag)
{
  __shared__ __align__(16) u16 As[128 * 32];
  __shared__ __align__(16) u16 Bs[128 * 32];
  const int tid  = threadIdx.x;
  const int lane = tid & 63;
  const int wave = tid >> 6;
  const int bm = blockIdx.x, bn = blockIdx.y;
  const int rw = lane >> 2;          // row within wave's 16-row group
  const int kq = (lane & 3) * 8;     // k element offset
  const int lo = lane & 15;
  const int quad = lane >> 4;
  const int wm = wave & 1, wn = wave >> 1;

  const u16* Ag = A  + (u64)(bm * 128 + wave * 16 + rw) * K + kq;
  const u16* Bg = Bw + (u64)(bn * 128 + wave * 16 + rw) * K + kq;
  u16* As0 = As + wave * 16 * 32;
  u16* Bs0 = Bs + wave * 16 * 32;

  f32x4 acc[4][4] = {};

  for (int k0 = 0; k0 < K; k0 += 32) {
    u16x8 a0 = *(const u16x8*)(Ag + k0);
    u16x8 a1 = *(const u16x8*)(Ag + (u64)64 * K + k0);
    u16x8 b0 = *(const u16x8*)(Bg + k0);
    u16x8 b1 = *(const u16x8*)(Bg + (u64)64 * K + k0);
    __syncthreads();
    *(u16x8*)(As0 + lane * 8) = a0;
    *(u16x8*)(As0 + 64 * 32 + lane * 8) = a1;
    *(u16x8*)(Bs0 + lane * 8) = b0;
    *(u16x8*)(Bs0 + 64 * 32 + lane * 8) = b1;
    __syncthreads();
    bf16x8 af[4], bq[4];
#pragma unroll
    for (int i = 0; i < 4; ++i)
      af[i] = ld8(As + (wm * 64 + i * 16 + lo) * 32 + quad * 8);
#pragma unroll
    for (int j = 0; j < 4; ++j)
      bq[j] = ld8(Bs + (wn * 64 + j * 16 + lo) * 32 + quad * 8);
#pragma unroll
    for (int i = 0; i < 4; ++i)
#pragma unroll
      for (int j = 0; j < 4; ++j)
        acc[i][j] = MFMA16(af[i], bq[j], acc[i][j]);
  }

  u16* C16 = (u16*)Cv;
  float* C32 = (float*)Cv;
  const int f = (MODE == 2) ? *flag : 1;
#pragma unroll
  for (int i = 0; i < 4; ++i)
#pragma unroll
    for (int j = 0; j < 4; ++j)
#pragma unroll
      for (int r = 0; r < 4; ++r) {
        int row = bm * 128 + wm * 64 + i * 16 + quad * 4 + r;
        int col = bn * 128 + wn * 64 + j * 16 + lo;
        u64 off = (u64)row * N + col;
        float v = acc[i][j][r];
        if (MODE >= 1) v += b2f(res[off]);
        if (MODE == 2 && f == 0) C32[off] = v;
        else C16[off] = f2b(v);
      }
}

// ---------------------------------------------------------------------------
// rmsnorm row kernel: out = x / sqrt(mean(x^2)+eps) * w   (bf16 in/out)
// ---------------------------------------------------------------------------
__global__ __launch_bounds__(256) void rmsnorm_k(
    const u16* __restrict__ x, const u16* __restrict__ w, u16* __restrict__ out)
{
  __shared__ float red[4];
  const int row = blockIdx.x, tid = threadIdx.x;
  const u16* xr = x + (u64)row * CC;
  u16x4 raw = *(const u16x4*)(xr + tid * 4);
  float v0 = b2f(raw[0]), v1 = b2f(raw[1]), v2 = b2f(raw[2]), v3 = b2f(raw[3]);
  float s = v0 * v0 + v1 * v1 + v2 * v2 + v3 * v3;
#pragma unroll
  for (int m = 1; m < 64; m <<= 1) s += __shfl_xor(s, m, 64);
  if ((tid & 63) == 0) red[tid >> 6] = s;
  __syncthreads();
  float tot = red[0] + red[1] + red[2] + red[3];
  float r = rsqrtf(tot * (1.0f / CC) + 1e-6f);
  const u16* wr = w + tid * 4;
  u16x4 o;
  o[0] = f2b(v0 * r * b2f(wr[0]));
  o[1] = f2b(v1 * r * b2f(wr[1]));
  o[2] = f2b(v2 * r * b2f(wr[2]));
  o[3] = f2b(v3 * r * b2f(wr[3]));
  *(u16x4*)(out + (u64)row * CC + tid * 4) = o;
}

// ---------------------------------------------------------------------------
// per-head l2 normalize in place: rows of 1024 = 16 heads x 64
// ---------------------------------------------------------------------------
__global__ __launch_bounds__(256) void l2norm_k(u16* __restrict__ q)
{
  const int row = blockIdx.x, tid = threadIdx.x;
  const int hh = tid >> 4, ss = tid & 15;
  u16* p = q + (u64)row * CC + hh * DD + ss * 4;
  u16x4 raw = *(const u16x4*)p;
  float v0 = b2f(raw[0]), v1 = b2f(raw[1]), v2 = b2f(raw[2]), v3 = b2f(raw[3]);
  float s = v0 * v0 + v1 * v1 + v2 * v2 + v3 * v3;
#pragma unroll
  for (int m = 1; m < 16; m <<= 1) s += __shfl_xor(s, m, 64);
  float sc = 1.0f / fmaxf(sqrtf(s), 1e-12f);
  u16x4 o;
  o[0] = f2b(v0 * sc); o[1] = f2b(v1 * sc);
  o[2] = f2b(v2 * sc); o[3] = f2b(v3 * sc);
  *(u16x4*)p = o;
}

// ---------------------------------------------------------------------------
// beta = sigmoid(xn @ bw^T + bb) : (8192 x 16) fp32
// ---------------------------------------------------------------------------
__global__ __launch_bounds__(256) void beta_k(
    const u16* __restrict__ xn, const u16* __restrict__ bw,
    const u16* __restrict__ bb, float* __restrict__ beta)
{
  const int row = blockIdx.x, tid = threadIdx.x;
  const int hh = tid >> 4, ss = tid & 15;
  const u16* xr = xn + (u64)row * CC + ss * 64;
  const u16* wr = bw + (u64)hh * CC + ss * 64;
  float s = 0.f;
#pragma unroll
  for (int j = 0; j < 8; ++j) {
    u16x8 a = *(const u16x8*)(xr + j * 8);
    u16x8 c = *(const u16x8*)(wr + j * 8);
#pragma unroll
    for (int e = 0; e < 8; ++e) s += b2f(a[e]) * b2f(c[e]);
  }
#pragma unroll
  for (int m = 1; m < 16; m <<= 1) s += __shfl_xor(s, m, 64);
  if (ss == 0) beta[(u64)row * HH + hh] = sigmoidf_(s + b2f(bb[hh]));
}

// ---------------------------------------------------------------------------
// chunk precompute (parallel over b,h,chunk):
//   A = strict_tril(diag(beta) K K^T)          (fp32, LDS)
//   Wneg = -(I+A)^-1 diag(beta) K              (bf16 -> ws)
//   U0   =  (I+A)^-1 diag(beta) V              (bf16 -> ws)
//   P    = strict_tril(Q K^T)                  (bf16 -> ws)
// ---------------------------------------------------------------------------
__global__ __launch_bounds__(256) void chunk_pre(
    const u16* __restrict__ qn, const u16* __restrict__ kn,
    const u16* __restrict__ vn, const float* __restrict__ beta,
    u16* __restrict__ wneg, u16* __restrict__ u0m, u16* __restrict__ pm)
{
  __shared__ __align__(16) u16 Qc[64 * LS], Kc[64 * LS], Vc[64 * LS];
  __shared__ float Af[64 * 64];
  __shared__ float bet[64];
  const int tid = threadIdx.x;
  const int lane = tid & 63, wave = tid >> 6;
  const int lo = lane & 15, quad = lane >> 4;
  const int bc = blockIdx.x;
  const int bh = bc >> 5, c = bc & 31;
  const int b = bh >> 4, h = bh & 15;
  const u64 gbase = ((u64)(b * TT + c * LCH) * HH + h) * DD;
  const u64 cb = (u64)bc * 4096;

#pragma unroll
  for (int it = 0; it < 2; ++it) {
    int idx = tid + it * 256;
    int t = idx >> 3, seg = (idx & 7) * 8;
    u64 g = gbase + (u64)t * CC + seg;
    *(u16x8*)(Qc + t * LS + seg) = *(const u16x8*)(qn + g);
    *(u16x8*)(Kc + t * LS + seg) = *(const u16x8*)(kn + g);
    *(u16x8*)(Vc + t * LS + seg) = *(const u16x8*)(vn + g);
  }
  if (tid < 64) bet[tid] = beta[(u64)(b * TT + c * LCH + tid) * HH + h];
  __syncthreads();

  { // A = strict_tril(diag(beta) K K^T), all 4 waves
    const int wm = wave & 1, wn = wave >> 1;
    f32x4 aa[2][2] = {};
#pragma unroll
    for (int k0 = 0; k0 < 64; k0 += 32) {
      bf16x8 af[2], bq[2];
#pragma unroll
      for (int i = 0; i < 2; ++i) af[i] = ld8(Kc + (wm * 32 + i * 16 + lo) * LS + k0 + quad * 8);
#pragma unroll
      for (int j = 0; j < 2; ++j) bq[j] = ld8(Kc + (wn * 32 + j * 16 + lo) * LS + k0 + quad * 8);
#pragma unroll
      for (int i = 0; i < 2; ++i)
#pragma unroll
        for (int j = 0; j < 2; ++j) aa[i][j] = MFMA16(af[i], bq[j], aa[i][j]);
    }
#pragma unroll
    for (int i = 0; i < 2; ++i)
#pragma unroll
      for (int j = 0; j < 2; ++j)
#pragma unroll
        for (int r = 0; r < 4; ++r) {
          int t = wm * 32 + i * 16 + quad * 4 + r;
          int s = wn * 32 + j * 16 + lo;
          Af[t * 64 + s] = (s < t) ? bet[t] * aa[i][j][r] : 0.0f;
        }
  }
  __syncthreads();

  if (wave < 2) {
    // forward substitution of (I+A); lane = column d; hist in registers
    const u16* src = (wave == 0) ? Kc : Vc;
    u16* dst = (wave == 0) ? wneg : u0m;
    const float sgn = (wave == 0) ? -1.0f : 1.0f;
    const int d = lane;
    float hist[64];
#pragma unroll
    for (int t = 0; t < 64; ++t) {
      float a = bet[t] * b2f(src[t * LS + d]);
#pragma unroll
      for (int s = 0; s < t; ++s) a -= Af[t * 64 + s] * hist[s];
      hist[t] = a;
      dst[cb + (u64)t * 64 + d] = f2b(sgn * a);
    }
  } else {
    // P = strict_tril(Q K^T); waves 2,3 split rows
    const int w2 = wave - 2;
    f32x4 ap[2][4] = {};
#pragma unroll
    for (int k0 = 0; k0 < 64; k0 += 32) {
      bf16x8 af[2], bq[4];
#pragma unroll
      for (int i = 0; i < 2; ++i) af[i] = ld8(Qc + (w2 * 32 + i * 16 + lo) * LS + k0 + quad * 8);
#pragma unroll
      for (int j = 0; j < 4; ++j) bq[j] = ld8(Kc + (j * 16 + lo) * LS + k0 + quad * 8);
#pragma unroll
      for (int i = 0; i < 2; ++i)
#pragma unroll
        for (int j = 0; j < 4; ++j) ap[i][j] = MFMA16(af[i], bq[j], ap[i][j]);
    }
#pragma unroll
    for (int i = 0; i < 2; ++i)
#pragma unroll
      for (int j = 0; j < 4; ++j)
#pragma unroll
        for (int r = 0; r < 4; ++r) {
          int t = w2 * 32 + i * 16 + quad * 4 + r;
          int s = j * 16 + lo;
          pm[cb + (u64)t * 64 + s] = f2b((s < t) ? ap[i][j][r] : 0.0f);
        }
  }
}

// 64x64x64 bf16 MFMA GEMM helper on LDS tiles (C[m,n] += sum_k A[m,k]*B[n,k])
__device__ __forceinline__ void gemm64_acc(
    f32x4 acc[2][2], const u16* Am, const u16* Bm,
    int wm, int wn, int lo, int quad)
{
#pragma unroll
  for (int k0 = 0; k0 < 64; k0 += 32) {
    bf16x8 af[2], bq[2];
#pragma unroll
    for (int i = 0; i < 2; ++i) af[i] = ld8(Am + (wm * 32 + i * 16 + lo) * LS + k0 + quad * 8);
#pragma unroll
    for (int j = 0; j < 2; ++j) bq[j] = ld8(Bm + (wn * 32 + j * 16 + lo) * LS + k0 + quad * 8);
#pragma unroll
    for (int i = 0; i < 2; ++i)
#pragma unroll
      for (int j = 0; j < 2; ++j) acc[i][j] = MFMA16(af[i], bq[j], acc[i][j]);
  }
}

// ---------------------------------------------------------------------------
// sequential chunk recurrence, one block per (b,h):
//   U = U0 + Wneg S^T ; O = Q S^T + P U ; S += U^T K   (S kept as M[dv,dk])
// ---------------------------------------------------------------------------
__global__ __launch_bounds__(256) void chunk_seq(
    const u16* __restrict__ qn, const u16* __restrict__ kn,
    const u16* __restrict__ wneg, const u16* __restrict__ u0m,
    const u16* __restrict__ pm, u16* __restrict__ ob)
{
  __shared__ __align__(16) u16 Qs[64 * LS], KTs[64 * LS], Ws[64 * LS],
      Ps[64 * LS], U0s[64 * LS], UTs[64 * LS], Sb[64 * LS];
  const int tid = threadIdx.x;
  const int lane = tid & 63, wave = tid >> 6;
  const int lo = lane & 15, quad = lane >> 4;
  const int wm = wave & 1, wn = wave >> 1;
  const int bh = blockIdx.x;
  const int b = bh >> 4, h = bh & 15;
  f32x4 Sacc[2][2] = {};
  for (int i = tid; i < 64 * LS; i += 256) Sb[i] = 0;
  __syncthreads();

#pragma unroll 1
  for (int c = 0; c < NCH; ++c) {
    const u64 gbase = ((u64)(b * TT + c * LCH) * HH + h) * DD;
    const u64 cb = (u64)(bh * NCH + c) * 4096;
#pragma unroll
    for (int it = 0; it < 2; ++it) {
      int idx = tid + it * 256;
      int t = idx >> 3, seg = (idx & 7) * 8;
      u64 g = gbase + (u64)t * CC + seg;
      *(u16x8*)(Qs + t * LS + seg) = *(const u16x8*)(qn + g);
      u16x8 kv = *(const u16x8*)(kn + g);
#pragma unroll
      for (int jj = 0; jj < 8; ++jj) KTs[(seg + jj) * LS + t] = kv[jj];
      *(u16x8*)(Ws + t * LS + seg)  = *(const u16x8*)(wneg + cb + t * 64 + seg);
      *(u16x8*)(Ps + t * LS + seg)  = *(const u16x8*)(pm + cb + t * 64 + seg);
      *(u16x8*)(U0s + t * LS + seg) = *(const u16x8*)(u0m + cb + t * 64 + seg);
    }
    __syncthreads();

    // U = U0 + Wneg * S^T
    f32x4 au[2][2];
#pragma unroll
    for (int i = 0; i < 2; ++i)
#pragma unroll
      for (int j = 0; j < 2; ++j)
#pragma unroll
        for (int r = 0; r < 4; ++r)
          au[i][j][r] = b2f(U0s[(wm * 32 + i * 16 + quad * 4 + r) * LS + wn * 32 + j * 16 + lo]);
    gemm64_acc(au, Ws, Sb, wm, wn, lo, quad);
#pragma unroll
    for (int i = 0; i < 2; ++i)
#pragma unroll
      for (int j = 0; j < 2; ++j)
#pragma unroll
        for (int r = 0; r < 4; ++r)
          UTs[(wn * 32 + j * 16 + lo) * LS + wm * 32 + i * 16 + quad * 4 + r] = f2b(au[i][j][r]);
    __syncthreads();

    // O = Q S^T + P U ; S += U^T K
    f32x4 ao[2][2] = {};
    gemm64_acc(ao, Qs, Sb, wm, wn, lo, quad);
    gemm64_acc(ao, Ps, UTs, wm, wn, lo, quad);
#pragma unroll
    for (int i = 0; i < 2; ++i)
#pragma unroll
      for (int j = 0; j < 2; ++j)
#pragma unroll
        for (int r = 0; r < 4; ++r)
          ob[gbase + (u64)(wm * 32 + i * 16 + quad * 4 + r) * CC + wn * 32 + j * 16 + lo] =
              f2b(ao[i][j][r]);
    gemm64_acc(Sacc, UTs, KTs, wm, wn, lo, quad);
    __syncthreads();

#pragma unroll
    for (int i = 0; i < 2; ++i)
#pragma unroll
      for (int j = 0; j < 2; ++j)
#pragma unroll
        for (int r = 0; r < 4; ++r)
          Sb[(wm * 32 + i * 16 + quad * 4 + r) * LS + wn * 32 + j * 16 + lo] = f2b(Sacc[i][j][r]);
    __syncthreads();
  }
}

// o *= sigmoid(g)
__global__ __launch_bounds__(256) void gate_mul_k(const u16* __restrict__ g,
                                                  u16* __restrict__ o, u64 n)
{
  u64 i = ((u64)blockIdx.x * 256 + threadIdx.x) * 8;
  if (i >= n) return;
  u16x8 gv = *(const u16x8*)(g + i);
  u16x8 ov = *(const u16x8*)(o + i);
  u16x8 r;
#pragma unroll
  for (int e = 0; e < 8; ++e)
    r[e] = f2b(sigmoidf_(b2f(gv[e])) * b2f(ov[e]));
  *(u16x8*)(o + i) = r;
}

// g = silu(g) * u
__global__ __launch_bounds__(256) void silu_mul_k(u16* __restrict__ g,
                                                  const u16* __restrict__ u, u64 n)
{
  u64 i = ((u64)blockIdx.x * 256 + threadIdx.x) * 8;
  if (i >= n) return;
  u16x8 gv = *(const u16x8*)(g + i);
  u16x8 uv = *(const u16x8*)(u + i);
  u16x8 r;
#pragma unroll
  for (int e = 0; e < 8; ++e) {
    float gg = b2f(gv[e]);
    r[e] = f2b(gg * sigmoidf_(gg) * b2f(uv[e]));
  }
  *(u16x8*)(g + i) = r;
}

extern "C" void kernel_launch(void* const* d_in, const int* in_sizes, int n_in,
                              void* d_out, int out_size, void* d_ws, size_t ws_size,
                              hipStream_t stream)
{
  (void)in_sizes; (void)n_in; (void)out_size; (void)ws_size;
  char* ws = (char*)d_ws;
  const u64 SZ = (u64)BT * CC * 2;            // 16 MiB
  const u64 MB = 1ull << 20;

  u16* xn1  = (u16*)(ws + 0 * SZ);
  u16* qb   = (u16*)(ws + 1 * SZ);
  u16* kb   = (u16*)(ws + 2 * SZ);
  u16* vb   = (u16*)(ws + 3 * SZ);
  u16* grw  = (u16*)(ws + 4 * SZ);
  u16* wneg = (u16*)(ws + 5 * SZ);
  u16* u0m  = (u16*)(ws + 6 * SZ);
  u16* pmm  = (u16*)(ws + 7 * SZ);
  u16* obf  = (u16*)(ws + 8 * SZ);            // attn out; later aliased as xn2
  u16* x2   = (u16*)(ws + 9 * SZ);
  float* beta = (float*)(ws + 10 * SZ);       // 512 KiB
  int*  flag  = (int*)(ws + 10 * SZ + 768 * 1024);
  char* CV = ws + 10 * SZ + MB;               // canonical bf16 copies
  u16* xc   = (u16*)(CV + 0 * MB);            // 16 MiB
  u16* qwc  = (u16*)(CV + 16 * MB);
  u16* kwc  = (u16*)(CV + 18 * MB);
  u16* vwc  = (u16*)(CV + 20 * MB);
  u16* gwc  = (u16*)(CV + 22 * MB);
  u16* owc  = (u16*)(CV + 24 * MB);
  u16* fgwc = (u16*)(CV + 26 * MB);
  u16* fuwc = (u16*)(CV + 34 * MB);
  u16* fdwc = (u16*)(CV + 42 * MB);
  u16* bwc  = (u16*)(CV + 50 * MB);
  u16* n1c  = (u16*)(CV + 50 * MB + 64 * 1024);
  u16* n2c  = (u16*)(CV + 50 * MB + 80 * 1024);
  u16* bbc  = (u16*)(CV + 50 * MB + 96 * 1024);
  u16* ffg  = (u16*)(ws + 0 * SZ);            // 64 MiB over xn1..vb (dead by then)
  u16* ffu  = (u16*)(ws + 4 * SZ);            // 64 MiB over grw..pmm (dead by then)
  u16* xn2  = obf;

  dim3 blk(256);
  dim3 g1(BT / 128, CC / 128);
  dim3 g2(BT / 128, FF / 128);
  u64 ne = (u64)BT * CC;
  u64 nf = (u64)BT * FF;

  detect_k<<<1, blk, 0, stream>>>((const u16*)d_in[0], flag);

  CvtArgs ca;
  ca.d[0]  = { d_in[0],  xc,   (u32)(BT * CC), 0 };
  ca.d[1]  = { d_in[5],  qwc,  (u32)(CC * CC), 0 };
  ca.d[2]  = { d_in[6],  kwc,  (u32)(CC * CC), 0 };
  ca.d[3]  = { d_in[7],  vwc,  (u32)(CC * CC), 0 };
  ca.d[4]  = { d_in[10], gwc,  (u32)(CC * CC), 0 };
  ca.d[5]  = { d_in[11], owc,  (u32)(CC * CC), 0 };
  ca.d[6]  = { d_in[12], fgwc, (u32)(FF * CC), 0 };
  ca.d[7]  = { d_in[13], fuwc, (u32)(FF * CC), 0 };
  ca.d[8]  = { d_in[14], fdwc, (u32)(CC * FF), 0 };
  ca.d[9]  = { d_in[8],  bwc,  (u32)(HH * CC), 0 };
  ca.d[10] = { d_in[3],  n1c,  (u32)CC, 0 };
  ca.d[11] = { d_in[4],  n2c,  (u32)CC, 0 };
  ca.d[12] = { d_in[9],  bbc,  (u32)HH, 0 };
  convert_k<<<dim3(4096, 13), blk, 0, stream>>>(ca, flag);

  rmsnorm_k<<<BT, blk, 0, stream>>>(xc, n1c, xn1);
  gemm_bt<0><<<g1, blk, 0, stream>>>(xn1, qwc, qb, nullptr, BT, CC, CC, nullptr);
  gemm_bt<0><<<g1, blk, 0, stream>>>(xn1, kwc, kb, nullptr, BT, CC, CC, nullptr);
  gemm_bt<0><<<g1, blk, 0, stream>>>(xn1, vwc, vb, nullptr, BT, CC, CC, nullptr);
  gemm_bt<0><<<g1, blk, 0, stream>>>(xn1, gwc, grw, nullptr, BT, CC, CC, nullptr);
  beta_k<<<BT, blk, 0, stream>>>(xn1, bwc, bbc, beta);
  l2norm_k<<<BT, blk, 0, stream>>>(qb);
  l2norm_k<<<BT, blk, 0, stream>>>(kb);
  chunk_pre<<<BQ * HH * NCH, blk, 0, stream>>>(qb, kb, vb, beta, wneg, u0m, pmm);
  chunk_seq<<<BQ * HH, blk, 0, stream>>>(qb, kb, wneg, u0m, pmm, obf);
  gate_mul_k<<<(unsigned)(ne / 8 / 256), blk, 0, stream>>>(grw, obf, ne);
  gemm_bt<1><<<g1, blk, 0, stream>>>(obf, owc, x2, xc, BT, CC, CC, nullptr);
  rmsnorm_k<<<BT, blk, 0, stream>>>(x2, n2c, xn2);
  gemm_bt<0><<<g2, blk, 0, stream>>>(xn2, fgwc, ffg, nullptr, BT, FF, CC, nullptr);
  gemm_bt<0><<<g2, blk, 0, stream>>>(xn2, fuwc, ffu, nullptr, BT, FF, CC, nullptr);
  silu_mul_k<<<(unsigned)(nf / 8 / 256), blk, 0, stream>>>(ffg, ffu, nf);
  gemm_bt<2><<<g1, blk, 0, stream>>>(ffg, fdwc, d_out, x2, BT, CC, FF, flag);
}

// Round 3
// 830.583 us; speedup vs baseline: 1.0129x; 1.0129x over previous
//
#include <hip/hip_runtime.h>
#include <stdint.h>

typedef unsigned short u16;
typedef unsigned int   u32;
typedef unsigned long long u64;

typedef __bf16 bf16x8 __attribute__((ext_vector_type(8)));
typedef u16    u16x8  __attribute__((ext_vector_type(8)));
typedef u16    u16x4  __attribute__((ext_vector_type(4)));
typedef float  f32x4  __attribute__((ext_vector_type(4)));

#define BQ 4
#define TT 2048
#define CC 1024
#define HH 16
#define DD 64
#define FF 4096
#define BT 8192      // B*T rows
#define NCH 32       // chunks per sequence
#define LCH 64       // chunk length
#define LS 72        // padded LDS stride for 64-wide tiles

__device__ __forceinline__ float b2f(u16 v) {
  u32 u = ((u32)v) << 16;
  return __builtin_bit_cast(float, u);
}
__device__ __forceinline__ u16 f2b(float f) {
  u32 u = __builtin_bit_cast(u32, f);
  u32 r = (u + 0x7fffu + ((u >> 16) & 1u)) >> 16;   // RNE
  return (u16)r;
}
__device__ __forceinline__ bf16x8 ld8(const u16* p) {
  return __builtin_bit_cast(bf16x8, *(const u16x8*)p);
}
__device__ __forceinline__ float sigmoidf_(float x) {
  return 1.0f / (1.0f + __expf(-x));
}

#define MFMA16(a, b, c) __builtin_amdgcn_mfma_f32_16x16x32_bf16(a, b, c, 0, 0, 0)

// async global->LDS, 16B/lane; HW writes lds_base + lane*16 (wave-uniform base)
__device__ __forceinline__ void stage16(const u16* g, u16* lds_base) {
  __builtin_amdgcn_global_load_lds(
      (const __attribute__((address_space(1))) u32*)(uintptr_t)g,
      (__attribute__((address_space(3))) u32*)lds_base, 16, 0, 0);
}

// fp32 -> bf16 weight canonicalization
struct Cvt { const float* src; u16* dst; u32 n; u32 pad; };
struct CvtArgs { Cvt d[12]; };

__global__ __launch_bounds__(256) void convert_k(CvtArgs a)
{
  const Cvt c = a.d[blockIdx.y];
  u64 i = ((u64)blockIdx.x * 256 + threadIdx.x) * 8;
  if (i >= c.n) return;
  f32x4 v0 = *(const f32x4*)(c.src + i);
  f32x4 v1 = *(const f32x4*)(c.src + i + 4);
  u16x8 o;
#pragma unroll
  for (int e = 0; e < 4; ++e) { o[e] = f2b(v0[e]); o[e + 4] = f2b(v1[e]); }
  *(u16x8*)(c.dst + i) = o;
}

// ---------------------------------------------------------------------------
// bf16 bt-GEMM: C[M,N] = A[M,K] * Bw[N,K]^T, 128x128 tile, BK=32,
// global_load_lds width-16 staging (m97 structure).
// MODE 0: bf16 out. MODE 1: + fp32 residual, bf16 out.
// MODE 2: + bf16 residual, fp32 out. MODE 3: out = silu(res_bf16)*acc, bf16.
// ---------------------------------------------------------------------------
template <int MODE>
__global__ __launch_bounds__(256) void gemm_bt(
    const u16* __restrict__ A, const u16* __restrict__ Bw,
    void* __restrict__ Cv, const void* __restrict__ res,
    int M, int N, int K)
{
  __shared__ __align__(16) u16 As[128 * 32];
  __shared__ __align__(16) u16 Bs[128 * 32];
  const int tid  = threadIdx.x;
  const int lane = tid & 63;
  const int wave = tid >> 6;
  const int bm = blockIdx.x, bn = blockIdx.y;
  const int rw = lane >> 2;          // row within wave's 16-row group
  const int kq = (lane & 3) * 8;     // k element offset
  const int lo = lane & 15;
  const int quad = lane >> 4;
  const int wm = wave & 1, wn = wave >> 1;

  const u16* Ag = A  + (u64)(bm * 128 + wave * 16 + rw) * K + kq;
  const u16* Bg = Bw + (u64)(bn * 128 + wave * 16 + rw) * K + kq;
  u16* As0 = As + wave * 16 * 32;
  u16* Bs0 = Bs + wave * 16 * 32;

  f32x4 acc[4][4] = {};

  for (int k0 = 0; k0 < K; k0 += 32) {
    stage16(Ag + k0, As0);
    stage16(Ag + (u64)64 * K + k0, As0 + 64 * 32);
    stage16(Bg + k0, Bs0);
    stage16(Bg + (u64)64 * K + k0, Bs0 + 64 * 32);
    __syncthreads();
    bf16x8 af[4], bq[4];
#pragma unroll
    for (int i = 0; i < 4; ++i)
      af[i] = ld8(As + (wm * 64 + i * 16 + lo) * 32 + quad * 8);
#pragma unroll
    for (int j = 0; j < 4; ++j)
      bq[j] = ld8(Bs + (wn * 64 + j * 16 + lo) * 32 + quad * 8);
#pragma unroll
    for (int i = 0; i < 4; ++i)
#pragma unroll
      for (int j = 0; j < 4; ++j)
        acc[i][j] = MFMA16(af[i], bq[j], acc[i][j]);
    __syncthreads();
  }

  u16* C16 = (u16*)Cv;
  float* C32 = (float*)Cv;
  const float* R32 = (const float*)res;
  const u16* R16 = (const u16*)res;
#pragma unroll
  for (int i = 0; i < 4; ++i)
#pragma unroll
    for (int j = 0; j < 4; ++j)
#pragma unroll
      for (int r = 0; r < 4; ++r) {
        int row = bm * 128 + wm * 64 + i * 16 + quad * 4 + r;
        int col = bn * 128 + wn * 64 + j * 16 + lo;
        u64 off = (u64)row * N + col;
        float v = acc[i][j][r];
        if (MODE == 1) { v += R32[off]; C16[off] = f2b(v); }
        else if (MODE == 2) { v += b2f(R16[off]); C32[off] = v; }
        else if (MODE == 3) {
          float g = b2f(R16[off]);
          C16[off] = f2b(g * sigmoidf_(g) * v);
        } else C16[off] = f2b(v);
      }
}

// ---------------------------------------------------------------------------
// rmsnorm: fp32 in, bf16 out
// ---------------------------------------------------------------------------
template <int IN32>
__global__ __launch_bounds__(256) void rmsnorm_k(
    const void* __restrict__ xv, const u16* __restrict__ w, u16* __restrict__ out)
{
  __shared__ float red[4];
  const int row = blockIdx.x, tid = threadIdx.x;
  float v0, v1, v2, v3;
  if (IN32) {
    f32x4 raw = *(const f32x4*)((const float*)xv + (u64)row * CC + tid * 4);
    v0 = raw[0]; v1 = raw[1]; v2 = raw[2]; v3 = raw[3];
  } else {
    u16x4 raw = *(const u16x4*)((const u16*)xv + (u64)row * CC + tid * 4);
    v0 = b2f(raw[0]); v1 = b2f(raw[1]); v2 = b2f(raw[2]); v3 = b2f(raw[3]);
  }
  float s = v0 * v0 + v1 * v1 + v2 * v2 + v3 * v3;
#pragma unroll
  for (int m = 1; m < 64; m <<= 1) s += __shfl_xor(s, m, 64);
  if ((tid & 63) == 0) red[tid >> 6] = s;
  __syncthreads();
  float tot = red[0] + red[1] + red[2] + red[3];
  float r = rsqrtf(tot * (1.0f / CC) + 1e-6f);
  const u16* wr = w + tid * 4;
  u16x4 o;
  o[0] = f2b(v0 * r * b2f(wr[0]));
  o[1] = f2b(v1 * r * b2f(wr[1]));
  o[2] = f2b(v2 * r * b2f(wr[2]));
  o[3] = f2b(v3 * r * b2f(wr[3]));
  *(u16x4*)(out + (u64)row * CC + tid * 4) = o;
}

// per-head l2 normalize in place
__global__ __launch_bounds__(256) void l2norm_k(u16* __restrict__ q)
{
  const int row = blockIdx.x, tid = threadIdx.x;
  const int hh = tid >> 4, ss = tid & 15;
  u16* p = q + (u64)row * CC + hh * DD + ss * 4;
  u16x4 raw = *(const u16x4*)p;
  float v0 = b2f(raw[0]), v1 = b2f(raw[1]), v2 = b2f(raw[2]), v3 = b2f(raw[3]);
  float s = v0 * v0 + v1 * v1 + v2 * v2 + v3 * v3;
#pragma unroll
  for (int m = 1; m < 16; m <<= 1) s += __shfl_xor(s, m, 64);
  float sc = 1.0f / fmaxf(sqrtf(s), 1e-12f);
  u16x4 o;
  o[0] = f2b(v0 * sc); o[1] = f2b(v1 * sc);
  o[2] = f2b(v2 * sc); o[3] = f2b(v3 * sc);
  *(u16x4*)p = o;
}

// beta = sigmoid(xn @ bw^T + bb)
__global__ __launch_bounds__(256) void beta_k(
    const u16* __restrict__ xn, const u16* __restrict__ bw,
    const u16* __restrict__ bb, float* __restrict__ beta)
{
  const int row = blockIdx.x, tid = threadIdx.x;
  const int hh = tid >> 4, ss = tid & 15;
  const u16* xr = xn + (u64)row * CC + ss * 64;
  const u16* wr = bw + (u64)hh * CC + ss * 64;
  float s = 0.f;
#pragma unroll
  for (int j = 0; j < 8; ++j) {
    u16x8 a = *(const u16x8*)(xr + j * 8);
    u16x8 c = *(const u16x8*)(wr + j * 8);
#pragma unroll
    for (int e = 0; e < 8; ++e) s += b2f(a[e]) * b2f(c[e]);
  }
#pragma unroll
  for (int m = 1; m < 16; m <<= 1) s += __shfl_xor(s, m, 64);
  if (ss == 0) beta[(u64)row * HH + hh] = sigmoidf_(s + b2f(bb[hh]));
}

// ---------------------------------------------------------------------------
// chunk precompute (parallel over b,h,chunk):
//   A = strict_tril(diag(beta) K K^T)
//   Wneg = -(I+A)^-1 diag(beta) K ; U0 = (I+A)^-1 diag(beta) V
//   P = strict_tril(Q K^T)
// ---------------------------------------------------------------------------
__global__ __launch_bounds__(256) void chunk_pre(
    const u16* __restrict__ qn, const u16* __restrict__ kn,
    const u16* __restrict__ vn, const float* __restrict__ beta,
    u16* __restrict__ wneg, u16* __restrict__ u0m, u16* __restrict__ pm)
{
  __shared__ __align__(16) u16 Qc[64 * LS], Kc[64 * LS], Vc[64 * LS];
  __shared__ float Af[64 * 64];
  __shared__ float bet[64];
  const int tid = threadIdx.x;
  const int lane = tid & 63, wave = tid >> 6;
  const int lo = lane & 15, quad = lane >> 4;
  const int bc = blockIdx.x;
  const int bh = bc >> 5, c = bc & 31;
  const int b = bh >> 4, h = bh & 15;
  const u64 gbase = ((u64)(b * TT + c * LCH) * HH + h) * DD;
  const u64 cb = (u64)bc * 4096;

#pragma unroll
  for (int it = 0; it < 2; ++it) {
    int idx = tid + it * 256;
    int t = idx >> 3, seg = (idx & 7) * 8;
    u64 g = gbase + (u64)t * CC + seg;
    *(u16x8*)(Qc + t * LS + seg) = *(const u16x8*)(qn + g);
    *(u16x8*)(Kc + t * LS + seg) = *(const u16x8*)(kn + g);
    *(u16x8*)(Vc + t * LS + seg) = *(const u16x8*)(vn + g);
  }
  if (tid < 64) bet[tid] = beta[(u64)(b * TT + c * LCH + tid) * HH + h];
  __syncthreads();

  { // A = strict_tril(diag(beta) K K^T)
    const int wm = wave & 1, wn = wave >> 1;
    f32x4 aa[2][2] = {};
#pragma unroll
    for (int k0 = 0; k0 < 64; k0 += 32) {
      bf16x8 af[2], bq[2];
#pragma unroll
      for (int i = 0; i < 2; ++i) af[i] = ld8(Kc + (wm * 32 + i * 16 + lo) * LS + k0 + quad * 8);
#pragma unroll
      for (int j = 0; j < 2; ++j) bq[j] = ld8(Kc + (wn * 32 + j * 16 + lo) * LS + k0 + quad * 8);
#pragma unroll
      for (int i = 0; i < 2; ++i)
#pragma unroll
        for (int j = 0; j < 2; ++j) aa[i][j] = MFMA16(af[i], bq[j], aa[i][j]);
    }
#pragma unroll
    for (int i = 0; i < 2; ++i)
#pragma unroll
      for (int j = 0; j < 2; ++j)
#pragma unroll
        for (int r = 0; r < 4; ++r) {
          int t = wm * 32 + i * 16 + quad * 4 + r;
          int s = wn * 32 + j * 16 + lo;
          Af[t * 64 + s] = (s < t) ? bet[t] * aa[i][j][r] : 0.0f;
        }
  }
  __syncthreads();

  if (wave < 2) {
    // forward substitution of (I+A); lane = column d
    const u16* src = (wave == 0) ? Kc : Vc;
    u16* dst = (wave == 0) ? wneg : u0m;
    const float sgn = (wave == 0) ? -1.0f : 1.0f;
    const int d = lane;
    float hist[64];
#pragma unroll
    for (int t = 0; t < 64; ++t) {
      float a = bet[t] * b2f(src[t * LS + d]);
#pragma unroll
      for (int s = 0; s < t; ++s) a -= Af[t * 64 + s] * hist[s];
      hist[t] = a;
      dst[cb + (u64)t * 64 + d] = f2b(sgn * a);
    }
  } else {
    // P = strict_tril(Q K^T)
    const int w2 = wave - 2;
    f32x4 ap[2][4] = {};
#pragma unroll
    for (int k0 = 0; k0 < 64; k0 += 32) {
      bf16x8 af[2], bq[4];
#pragma unroll
      for (int i = 0; i < 2; ++i) af[i] = ld8(Qc + (w2 * 32 + i * 16 + lo) * LS + k0 + quad * 8);
#pragma unroll
      for (int j = 0; j < 4; ++j) bq[j] = ld8(Kc + (j * 16 + lo) * LS + k0 + quad * 8);
#pragma unroll
      for (int i = 0; i < 2; ++i)
#pragma unroll
        for (int j = 0; j < 4; ++j) ap[i][j] = MFMA16(af[i], bq[j], ap[i][j]);
    }
#pragma unroll
    for (int i = 0; i < 2; ++i)
#pragma unroll
      for (int j = 0; j < 4; ++j)
#pragma unroll
        for (int r = 0; r < 4; ++r) {
          int t = w2 * 32 + i * 16 + quad * 4 + r;
          int s = j * 16 + lo;
          pm[cb + (u64)t * 64 + s] = f2b((s < t) ? ap[i][j][r] : 0.0f);
        }
  }
}

// ---------------------------------------------------------------------------
// sequential chunk recurrence, split 4-way over dv: block = (bh, dv-quarter).
// Per chunk: Uq = U0q + Wneg Sq^T ; Oq = Q Sq^T + P Uq ; Sq += Uq^T K.
// Sq is the dv-quarter rows [16 x 64] of the state, held in acc regs + LDS.
// ---------------------------------------------------------------------------
__global__ __launch_bounds__(256) void chunk_seq(
    const u16* __restrict__ qn, const u16* __restrict__ kn,
    const u16* __restrict__ wneg, const u16* __restrict__ u0m,
    const u16* __restrict__ pm, u16* __restrict__ ob)
{
  __shared__ __align__(16) u16 Qs[64 * LS], KTs[64 * LS], Ws[64 * LS], Ps[64 * LS];
  __shared__ __align__(16) u16 U0q[64 * 16];
  __shared__ __align__(16) u16 Sq[16 * LS], UTq[16 * LS];
  const int tid = threadIdx.x;
  const int lane = tid & 63, wave = tid >> 6;
  const int lo = lane & 15, quad = lane >> 4;
  const int blk = blockIdx.x;
  const int bh = blk >> 2, q = blk & 3;
  const int b = bh >> 4, h = bh & 15;
  f32x4 Sacc = {};   // this wave's [dv=quad*4+r(16 rows via lanes), dk tile=wave] block

  for (int i = tid; i < 16 * LS; i += 256) Sq[i] = 0;
  __syncthreads();

#pragma unroll 1
  for (int c = 0; c < NCH; ++c) {
    const u64 gbase = ((u64)(b * TT + c * LCH) * HH + h) * DD;
    const u64 cb = (u64)(bh * NCH + c) * 4096;
#pragma unroll
    for (int it = 0; it < 2; ++it) {
      int idx = tid + it * 256;
      int t = idx >> 3, seg = (idx & 7) * 8;
      u64 g = gbase + (u64)t * CC + seg;
      *(u16x8*)(Qs + t * LS + seg) = *(const u16x8*)(qn + g);
      u16x8 kv = *(const u16x8*)(kn + g);
#pragma unroll
      for (int jj = 0; jj < 8; ++jj) KTs[(seg + jj) * LS + t] = kv[jj];
      *(u16x8*)(Ws + t * LS + seg) = *(const u16x8*)(wneg + cb + t * 64 + seg);
      *(u16x8*)(Ps + t * LS + seg) = *(const u16x8*)(pm + cb + t * 64 + seg);
    }
    if (tid < 128) {
      int t = tid >> 1, half = (tid & 1) * 8;
      *(u16x8*)(U0q + t * 16 + half) =
          *(const u16x8*)(u0m + cb + t * 64 + q * 16 + half);
    }
    __syncthreads();

    // Phase A: Uq[t, dv16] = U0q + Wneg * Sq^T  (wave = t-tile)
    f32x4 au;
#pragma unroll
    for (int r = 0; r < 4; ++r)
      au[r] = b2f(U0q[(wave * 16 + quad * 4 + r) * 16 + lo]);
#pragma unroll
    for (int k0 = 0; k0 < 64; k0 += 32) {
      bf16x8 af = ld8(Ws + (wave * 16 + lo) * LS + k0 + quad * 8);
      bf16x8 bq = ld8(Sq + lo * LS + k0 + quad * 8);
      au = MFMA16(af, bq, au);
    }
    // write Uq transposed: UTq[dv, t]
#pragma unroll
    for (int r = 0; r < 4; ++r)
      UTq[lo * LS + wave * 16 + quad * 4 + r] = f2b(au[r]);
    __syncthreads();

    // Phase B: Oq = Q Sq^T + P Uq  (Uq as B-operand == UTq rows)
    f32x4 ao = {};
#pragma unroll
    for (int k0 = 0; k0 < 64; k0 += 32) {
      bf16x8 af = ld8(Qs + (wave * 16 + lo) * LS + k0 + quad * 8);
      bf16x8 bq = ld8(Sq + lo * LS + k0 + quad * 8);
      ao = MFMA16(af, bq, ao);
    }
#pragma unroll
    for (int k0 = 0; k0 < 64; k0 += 32) {
      bf16x8 af = ld8(Ps + (wave * 16 + lo) * LS + k0 + quad * 8);
      bf16x8 bq = ld8(UTq + lo * LS + k0 + quad * 8);
      ao = MFMA16(af, bq, ao);
    }
#pragma unroll
    for (int r = 0; r < 4; ++r)
      ob[gbase + (u64)(wave * 16 + quad * 4 + r) * CC + q * 16 + lo] = f2b(ao[r]);

    // S update: Sq[dv, dk-tile wave] += Uq^T K
#pragma unroll
    for (int k0 = 0; k0 < 64; k0 += 32) {
      bf16x8 af = ld8(UTq + lo * LS + k0 + quad * 8);
      bf16x8 bq = ld8(KTs + (wave * 16 + lo) * LS + k0 + quad * 8);
      Sacc = MFMA16(af, bq, Sacc);
    }
    __syncthreads();
#pragma unroll
    for (int r = 0; r < 4; ++r)
      Sq[(quad * 4 + r) * LS + wave * 16 + lo] = f2b(Sacc[r]);
    __syncthreads();
  }
}

// o *= sigmoid(g)
__global__ __launch_bounds__(256) void gate_mul_k(const u16* __restrict__ g,
                                                  u16* __restrict__ o, u64 n)
{
  u64 i = ((u64)blockIdx.x * 256 + threadIdx.x) * 8;
  if (i >= n) return;
  u16x8 gv = *(const u16x8*)(g + i);
  u16x8 ov = *(const u16x8*)(o + i);
  u16x8 r;
#pragma unroll
  for (int e = 0; e < 8; ++e)
    r[e] = f2b(sigmoidf_(b2f(gv[e])) * b2f(ov[e]));
  *(u16x8*)(o + i) = r;
}

extern "C" void kernel_launch(void* const* d_in, const int* in_sizes, int n_in,
                              void* d_out, int out_size, void* d_ws, size_t ws_size,
                              hipStream_t stream)
{
  (void)in_sizes; (void)n_in; (void)out_size; (void)ws_size;
  const float* x32 = (const float*)d_in[0];
  char* ws = (char*)d_ws;
  const u64 SZ = (u64)BT * CC * 2;            // 16 MiB
  const u64 MB = 1ull << 20;

  u16* xn1  = (u16*)(ws + 0 * SZ);
  u16* qb   = (u16*)(ws + 1 * SZ);
  u16* kb   = (u16*)(ws + 2 * SZ);
  u16* vb   = (u16*)(ws + 3 * SZ);
  u16* grw  = (u16*)(ws + 4 * SZ);
  u16* wneg = (u16*)(ws + 5 * SZ);
  u16* u0m  = (u16*)(ws + 6 * SZ);
  u16* pmm  = (u16*)(ws + 7 * SZ);
  u16* obf  = (u16*)(ws + 8 * SZ);            // attn out; later aliased as xn2
  u16* x2   = (u16*)(ws + 9 * SZ);
  float* beta = (float*)(ws + 10 * SZ);       // 512 KiB
  char* CV  = ws + 10 * SZ + MB;              // canonical bf16 weights
  u16* qwc  = (u16*)(CV + 0 * MB);
  u16* kwc  = (u16*)(CV + 2 * MB);
  u16* vwc  = (u16*)(CV + 4 * MB);
  u16* gwc  = (u16*)(CV + 6 * MB);
  u16* owc  = (u16*)(CV + 8 * MB);
  u16* fgwc = (u16*)(CV + 10 * MB);
  u16* fuwc = (u16*)(CV + 18 * MB);
  u16* fdwc = (u16*)(CV + 26 * MB);
  u16* bwc  = (u16*)(CV + 34 * MB);
  u16* n1c  = (u16*)(CV + 34 * MB + 64 * 1024);
  u16* n2c  = (u16*)(CV + 34 * MB + 80 * 1024);
  u16* bbc  = (u16*)(CV + 34 * MB + 96 * 1024);
  u16* ffg  = (u16*)(ws + 0 * SZ);            // 64 MiB over xn1..vb (dead by then)
  u16* ffu  = (u16*)(ws + 4 * SZ);            // 64 MiB over grw..pmm (dead by then)
  u16* xn2  = obf;

  dim3 blk(256);
  dim3 g1(BT / 128, CC / 128);
  dim3 g2(BT / 128, FF / 128);
  u64 ne = (u64)BT * CC;

  CvtArgs ca;
  ca.d[0]  = { (const float*)d_in[5],  qwc,  (u32)(CC * CC), 0 };
  ca.d[1]  = { (const float*)d_in[6],  kwc,  (u32)(CC * CC), 0 };
  ca.d[2]  = { (const float*)d_in[7],  vwc,  (u32)(CC * CC), 0 };
  ca.d[3]  = { (const float*)d_in[10], gwc,  (u32)(CC * CC), 0 };
  ca.d[4]  = { (const float*)d_in[11], owc,  (u32)(CC * CC), 0 };
  ca.d[5]  = { (const float*)d_in[12], fgwc, (u32)(FF * CC), 0 };
  ca.d[6]  = { (const float*)d_in[13], fuwc, (u32)(FF * CC), 0 };
  ca.d[7]  = { (const float*)d_in[14], fdwc, (u32)(CC * FF), 0 };
  ca.d[8]  = { (const float*)d_in[8],  bwc,  (u32)(HH * CC), 0 };
  ca.d[9]  = { (const float*)d_in[3],  n1c,  (u32)CC, 0 };
  ca.d[10] = { (const float*)d_in[4],  n2c,  (u32)CC, 0 };
  ca.d[11] = { (const float*)d_in[9],  bbc,  (u32)HH, 0 };
  convert_k<<<dim3(2048, 12), blk, 0, stream>>>(ca);

  rmsnorm_k<1><<<BT, blk, 0, stream>>>(x32, n1c, xn1);
  gemm_bt<0><<<g1, blk, 0, stream>>>(xn1, qwc, qb, nullptr, BT, CC, CC);
  gemm_bt<0><<<g1, blk, 0, stream>>>(xn1, kwc, kb, nullptr, BT, CC, CC);
  gemm_bt<0><<<g1, blk, 0, stream>>>(xn1, vwc, vb, nullptr, BT, CC, CC);
  gemm_bt<0><<<g1, blk, 0, stream>>>(xn1, gwc, grw, nullptr, BT, CC, CC);
  beta_k<<<BT, blk, 0, stream>>>(xn1, bwc, bbc, beta);
  l2norm_k<<<BT, blk, 0, stream>>>(qb);
  l2norm_k<<<BT, blk, 0, stream>>>(kb);
  chunk_pre<<<BQ * HH * NCH, blk, 0, stream>>>(qb, kb, vb, beta, wneg, u0m, pmm);
  chunk_seq<<<BQ * HH * 4, blk, 0, stream>>>(qb, kb, wneg, u0m, pmm, obf);
  gate_mul_k<<<(unsigned)(ne / 8 / 256), blk, 0, stream>>>(grw, obf, ne);
  gemm_bt<1><<<g1, blk, 0, stream>>>(obf, owc, x2, x32, BT, CC, CC);
  rmsnorm_k<0><<<BT, blk, 0, stream>>>(x2, n2c, xn2);
  gemm_bt<0><<<g2, blk, 0, stream>>>(xn2, fgwc, ffg, nullptr, BT, FF, CC);
  gemm_bt<3><<<g2, blk, 0, stream>>>(xn2, fuwc, ffg, ffg, BT, FF, CC);
  gemm_bt<2><<<g1, blk, 0, stream>>>(ffg, fdwc, d_out, x2, BT, CC, FF);
}

// Round 4
// 767.034 us; speedup vs baseline: 1.0969x; 1.0829x over previous
//
#include <hip/hip_runtime.h>
#include <stdint.h>

typedef unsigned short u16;
typedef unsigned int   u32;
typedef unsigned long long u64;

typedef __bf16 bf16x8 __attribute__((ext_vector_type(8)));
typedef u16    u16x8  __attribute__((ext_vector_type(8)));
typedef u16    u16x4  __attribute__((ext_vector_type(4)));
typedef float  f32x4  __attribute__((ext_vector_type(4)));

#define BQ 4
#define TT 2048
#define CC 1024
#define HH 16
#define DD 64
#define FF 4096
#define BT 8192      // B*T rows
#define NCH 32       // chunks per sequence
#define LCH 64       // chunk length
#define LS 72        // padded LDS stride for 64-wide tiles
#define SE 140       // epilogue LDS stride (bank-shift 6/row -> conflict-free)

__device__ __forceinline__ float b2f(u16 v) {
  u32 u = ((u32)v) << 16;
  return __builtin_bit_cast(float, u);
}
__device__ __forceinline__ u16 f2b(float f) {
  u32 u = __builtin_bit_cast(u32, f);
  u32 r = (u + 0x7fffu + ((u >> 16) & 1u)) >> 16;   // RNE
  return (u16)r;
}
__device__ __forceinline__ bf16x8 ld8(const u16* p) {
  return __builtin_bit_cast(bf16x8, *(const u16x8*)p);
}
__device__ __forceinline__ float sigmoidf_(float x) {
  return 1.0f / (1.0f + __expf(-x));
}

#define MFMA16(a, b, c) __builtin_amdgcn_mfma_f32_16x16x32_bf16(a, b, c, 0, 0, 0)

// async global->LDS, 16B/lane; HW writes lds_base + lane*16 (wave-uniform base)
__device__ __forceinline__ void stage16(const u16* g, u16* lds_base) {
  __builtin_amdgcn_global_load_lds(
      (const __attribute__((address_space(1))) u32*)(uintptr_t)g,
      (__attribute__((address_space(3))) u32*)lds_base, 16, 0, 0);
}

// fp32 -> bf16 weight canonicalization
struct Cvt { const float* src; u16* dst; u32 n; u32 pad; };
struct CvtArgs { Cvt d[12]; };

__global__ __launch_bounds__(256) void convert_k(CvtArgs a)
{
  const Cvt c = a.d[blockIdx.y];
  u64 i = ((u64)blockIdx.x * 256 + threadIdx.x) * 8;
  if (i >= c.n) return;
  f32x4 v0 = *(const f32x4*)(c.src + i);
  f32x4 v1 = *(const f32x4*)(c.src + i + 4);
  u16x8 o;
#pragma unroll
  for (int e = 0; e < 4; ++e) { o[e] = f2b(v0[e]); o[e + 4] = f2b(v1[e]); }
  *(u16x8*)(c.dst + i) = o;
}

// ---------------------------------------------------------------------------
// bf16 bt-GEMM: C[M,N] = A[M,K] * Bw[N,K]^T, 128x128 tile, BK=32.
// Double-buffered global_load_lds K-loop, ONE barrier per iteration.
// Epilogue (MODE 0/1/3): acc -> bf16 LDS tile (stride SE) -> coalesced 16B
// stores. MODE 2 (fp32 out + bf16 residual) keeps direct scattered stores.
//   MODE 0: bf16 out. MODE 1: + fp32 residual, bf16 out.
//   MODE 2: + bf16 residual, fp32 out. MODE 3: out = silu(res_bf16)*acc, bf16.
// ---------------------------------------------------------------------------
template <int MODE>
__global__ __launch_bounds__(256) void gemm_bt(
    const u16* __restrict__ A, const u16* __restrict__ Bw,
    void* __restrict__ Cv, const void* __restrict__ res,
    int M, int N, int K)
{
  __shared__ __align__(16) u16 smem[128 * SE];   // 35 KiB; staging uses 32 KiB
  const int tid  = threadIdx.x;
  const int lane = tid & 63;
  const int wave = tid >> 6;
  const int bm = blockIdx.x, bn = blockIdx.y;
  const int rw = lane >> 2;          // row within wave's 16-row staging group
  const int kq = (lane & 3) * 8;     // k element offset
  const int lo = lane & 15;
  const int quad = lane >> 4;
  const int wm = wave & 1, wn = wave >> 1;

  const u16* Ag = A  + (u64)(bm * 128 + wave * 16 + rw) * K + kq;
  const u16* Bg = Bw + (u64)(bn * 128 + wave * 16 + rw) * K + kq;
  // buffers: A0 | A1 | B0 | B1, each 128*32 u16
  u16* const Ab[2] = { smem + wave * 512, smem + 4096 + wave * 512 };
  u16* const Bb[2] = { smem + 8192 + wave * 512, smem + 12288 + wave * 512 };

  f32x4 acc[4][4] = {};
  const int niter = K >> 5;

  // pre-stage iteration 0 into buffer 0
  stage16(Ag, Ab[0]);
  stage16(Ag + (u64)64 * K, Ab[0] + 2048);
  stage16(Bg, Bb[0]);
  stage16(Bg + (u64)64 * K, Bb[0] + 2048);

  int cur = 0;
  for (int it = 0; it < niter; ++it) {
    __syncthreads();                  // buf[cur] staged; buf[cur^1] free
    if (it + 1 < niter) {
      int kn = (it + 1) << 5;
      stage16(Ag + kn, Ab[cur ^ 1]);
      stage16(Ag + (u64)64 * K + kn, Ab[cur ^ 1] + 2048);
      stage16(Bg + kn, Bb[cur ^ 1]);
      stage16(Bg + (u64)64 * K + kn, Bb[cur ^ 1] + 2048);
    }
    const u16* Ac = smem + cur * 4096;
    const u16* Bc = smem + 8192 + cur * 4096;
    bf16x8 af[4], bq[4];
#pragma unroll
    for (int i = 0; i < 4; ++i)
      af[i] = ld8(Ac + (wm * 64 + i * 16 + lo) * 32 + quad * 8);
#pragma unroll
    for (int j = 0; j < 4; ++j)
      bq[j] = ld8(Bc + (wn * 64 + j * 16 + lo) * 32 + quad * 8);
#pragma unroll
    for (int i = 0; i < 4; ++i)
#pragma unroll
      for (int j = 0; j < 4; ++j)
        acc[i][j] = MFMA16(af[i], bq[j], acc[i][j]);
    cur ^= 1;
  }

  if (MODE == 2) {
    const u16* R16 = (const u16*)res;
    float* C32 = (float*)Cv;
#pragma unroll
    for (int i = 0; i < 4; ++i)
#pragma unroll
      for (int j = 0; j < 4; ++j)
#pragma unroll
        for (int r = 0; r < 4; ++r) {
          int row = bm * 128 + wm * 64 + i * 16 + quad * 4 + r;
          int col = bn * 128 + wn * 64 + j * 16 + lo;
          u64 off = (u64)row * N + col;
          C32[off] = acc[i][j][r] + b2f(R16[off]);
        }
    return;
  }

  // swizzled epilogue: acc -> LDS bf16 -> coalesced stores
  __syncthreads();                    // all ds_reads of smem done
#pragma unroll
  for (int i = 0; i < 4; ++i)
#pragma unroll
    for (int j = 0; j < 4; ++j)
#pragma unroll
      for (int r = 0; r < 4; ++r)
        smem[(wm * 64 + i * 16 + quad * 4 + r) * SE + wn * 64 + j * 16 + lo] =
            f2b(acc[i][j][r]);
  __syncthreads();

  u16* C16 = (u16*)Cv;
  const float* R32 = (const float*)res;
  const u16* R16 = (const u16*)res;
  const int orow = tid >> 4, ocol = (tid & 15) * 8;
#pragma unroll
  for (int w = 0; w < 8; ++w) {
    int rl = orow + w * 16;
    u16x8 v = *(const u16x8*)(smem + rl * SE + ocol);
    u64 off = (u64)(bm * 128 + rl) * N + bn * 128 + ocol;
    if (MODE == 0) {
      *(u16x8*)(C16 + off) = v;
    } else if (MODE == 1) {
      f32x4 r0 = *(const f32x4*)(R32 + off);
      f32x4 r1 = *(const f32x4*)(R32 + off + 4);
      u16x8 o;
#pragma unroll
      for (int e = 0; e < 4; ++e) {
        o[e]     = f2b(b2f(v[e])     + r0[e]);
        o[e + 4] = f2b(b2f(v[e + 4]) + r1[e]);
      }
      *(u16x8*)(C16 + off) = o;
    } else {                                   // MODE 3
      u16x8 g = *(const u16x8*)(R16 + off);
      u16x8 o;
#pragma unroll
      for (int e = 0; e < 8; ++e) {
        float gg = b2f(g[e]);
        o[e] = f2b(gg * sigmoidf_(gg) * b2f(v[e]));
      }
      *(u16x8*)(C16 + off) = o;
    }
  }
}

// ---------------------------------------------------------------------------
// rmsnorm: fp32/bf16 in, bf16 out
// ---------------------------------------------------------------------------
template <int IN32>
__global__ __launch_bounds__(256) void rmsnorm_k(
    const void* __restrict__ xv, const u16* __restrict__ w, u16* __restrict__ out)
{
  __shared__ float red[4];
  const int row = blockIdx.x, tid = threadIdx.x;
  float v0, v1, v2, v3;
  if (IN32) {
    f32x4 raw = *(const f32x4*)((const float*)xv + (u64)row * CC + tid * 4);
    v0 = raw[0]; v1 = raw[1]; v2 = raw[2]; v3 = raw[3];
  } else {
    u16x4 raw = *(const u16x4*)((const u16*)xv + (u64)row * CC + tid * 4);
    v0 = b2f(raw[0]); v1 = b2f(raw[1]); v2 = b2f(raw[2]); v3 = b2f(raw[3]);
  }
  float s = v0 * v0 + v1 * v1 + v2 * v2 + v3 * v3;
#pragma unroll
  for (int m = 1; m < 64; m <<= 1) s += __shfl_xor(s, m, 64);
  if ((tid & 63) == 0) red[tid >> 6] = s;
  __syncthreads();
  float tot = red[0] + red[1] + red[2] + red[3];
  float r = rsqrtf(tot * (1.0f / CC) + 1e-6f);
  const u16* wr = w + tid * 4;
  u16x4 o;
  o[0] = f2b(v0 * r * b2f(wr[0]));
  o[1] = f2b(v1 * r * b2f(wr[1]));
  o[2] = f2b(v2 * r * b2f(wr[2]));
  o[3] = f2b(v3 * r * b2f(wr[3]));
  *(u16x4*)(out + (u64)row * CC + tid * 4) = o;
}

// per-head l2 normalize in place
__global__ __launch_bounds__(256) void l2norm_k(u16* __restrict__ q)
{
  const int row = blockIdx.x, tid = threadIdx.x;
  const int hh = tid >> 4, ss = tid & 15;
  u16* p = q + (u64)row * CC + hh * DD + ss * 4;
  u16x4 raw = *(const u16x4*)p;
  float v0 = b2f(raw[0]), v1 = b2f(raw[1]), v2 = b2f(raw[2]), v3 = b2f(raw[3]);
  float s = v0 * v0 + v1 * v1 + v2 * v2 + v3 * v3;
#pragma unroll
  for (int m = 1; m < 16; m <<= 1) s += __shfl_xor(s, m, 64);
  float sc = 1.0f / fmaxf(sqrtf(s), 1e-12f);
  u16x4 o;
  o[0] = f2b(v0 * sc); o[1] = f2b(v1 * sc);
  o[2] = f2b(v2 * sc); o[3] = f2b(v3 * sc);
  *(u16x4*)p = o;
}

// beta = sigmoid(xn @ bw^T + bb)
__global__ __launch_bounds__(256) void beta_k(
    const u16* __restrict__ xn, const u16* __restrict__ bw,
    const u16* __restrict__ bb, float* __restrict__ beta)
{
  const int row = blockIdx.x, tid = threadIdx.x;
  const int hh = tid >> 4, ss = tid & 15;
  const u16* xr = xn + (u64)row * CC + ss * 64;
  const u16* wr = bw + (u64)hh * CC + ss * 64;
  float s = 0.f;
#pragma unroll
  for (int j = 0; j < 8; ++j) {
    u16x8 a = *(const u16x8*)(xr + j * 8);
    u16x8 c = *(const u16x8*)(wr + j * 8);
#pragma unroll
    for (int e = 0; e < 8; ++e) s += b2f(a[e]) * b2f(c[e]);
  }
#pragma unroll
  for (int m = 1; m < 16; m <<= 1) s += __shfl_xor(s, m, 64);
  if (ss == 0) beta[(u64)row * HH + hh] = sigmoidf_(s + b2f(bb[hh]));
}

// ---------------------------------------------------------------------------
// chunk precompute (parallel over b,h,chunk):
//   A = strict_tril(diag(beta) K K^T)
//   Wneg = -(I+A)^-1 diag(beta) K ; U0 = (I+A)^-1 diag(beta) V
//   P = strict_tril(Q K^T)
// ---------------------------------------------------------------------------
__global__ __launch_bounds__(256) void chunk_pre(
    const u16* __restrict__ qn, const u16* __restrict__ kn,
    const u16* __restrict__ vn, const float* __restrict__ beta,
    u16* __restrict__ wneg, u16* __restrict__ u0m, u16* __restrict__ pm)
{
  __shared__ __align__(16) u16 Qc[64 * LS], Kc[64 * LS], Vc[64 * LS];
  __shared__ float Af[64 * 64];
  __shared__ float bet[64];
  const int tid = threadIdx.x;
  const int lane = tid & 63, wave = tid >> 6;
  const int lo = lane & 15, quad = lane >> 4;
  const int bc = blockIdx.x;
  const int bh = bc >> 5, c = bc & 31;
  const int b = bh >> 4, h = bh & 15;
  const u64 gbase = ((u64)(b * TT + c * LCH) * HH + h) * DD;
  const u64 cb = (u64)bc * 4096;

#pragma unroll
  for (int it = 0; it < 2; ++it) {
    int idx = tid + it * 256;
    int t = idx >> 3, seg = (idx & 7) * 8;
    u64 g = gbase + (u64)t * CC + seg;
    *(u16x8*)(Qc + t * LS + seg) = *(const u16x8*)(qn + g);
    *(u16x8*)(Kc + t * LS + seg) = *(const u16x8*)(kn + g);
    *(u16x8*)(Vc + t * LS + seg) = *(const u16x8*)(vn + g);
  }
  if (tid < 64) bet[tid] = beta[(u64)(b * TT + c * LCH + tid) * HH + h];
  __syncthreads();

  { // A = strict_tril(diag(beta) K K^T)
    const int wm = wave & 1, wn = wave >> 1;
    f32x4 aa[2][2] = {};
#pragma unroll
    for (int k0 = 0; k0 < 64; k0 += 32) {
      bf16x8 af[2], bq[2];
#pragma unroll
      for (int i = 0; i < 2; ++i) af[i] = ld8(Kc + (wm * 32 + i * 16 + lo) * LS + k0 + quad * 8);
#pragma unroll
      for (int j = 0; j < 2; ++j) bq[j] = ld8(Kc + (wn * 32 + j * 16 + lo) * LS + k0 + quad * 8);
#pragma unroll
      for (int i = 0; i < 2; ++i)
#pragma unroll
        for (int j = 0; j < 2; ++j) aa[i][j] = MFMA16(af[i], bq[j], aa[i][j]);
    }
#pragma unroll
    for (int i = 0; i < 2; ++i)
#pragma unroll
      for (int j = 0; j < 2; ++j)
#pragma unroll
        for (int r = 0; r < 4; ++r) {
          int t = wm * 32 + i * 16 + quad * 4 + r;
          int s = wn * 32 + j * 16 + lo;
          Af[t * 64 + s] = (s < t) ? bet[t] * aa[i][j][r] : 0.0f;
        }
  }
  __syncthreads();

  if (wave < 2) {
    // forward substitution of (I+A); lane = column d
    const u16* src = (wave == 0) ? Kc : Vc;
    u16* dst = (wave == 0) ? wneg : u0m;
    const float sgn = (wave == 0) ? -1.0f : 1.0f;
    const int d = lane;
    float hist[64];
#pragma unroll
    for (int t = 0; t < 64; ++t) {
      float a = bet[t] * b2f(src[t * LS + d]);
#pragma unroll
      for (int s = 0; s < t; ++s) a -= Af[t * 64 + s] * hist[s];
      hist[t] = a;
      dst[cb + (u64)t * 64 + d] = f2b(sgn * a);
    }
  } else {
    // P = strict_tril(Q K^T)
    const int w2 = wave - 2;
    f32x4 ap[2][4] = {};
#pragma unroll
    for (int k0 = 0; k0 < 64; k0 += 32) {
      bf16x8 af[2], bq[4];
#pragma unroll
      for (int i = 0; i < 2; ++i) af[i] = ld8(Qc + (w2 * 32 + i * 16 + lo) * LS + k0 + quad * 8);
#pragma unroll
      for (int j = 0; j < 4; ++j) bq[j] = ld8(Kc + (j * 16 + lo) * LS + k0 + quad * 8);
#pragma unroll
      for (int i = 0; i < 2; ++i)
#pragma unroll
        for (int j = 0; j < 4; ++j) ap[i][j] = MFMA16(af[i], bq[j], ap[i][j]);
    }
#pragma unroll
    for (int i = 0; i < 2; ++i)
#pragma unroll
      for (int j = 0; j < 4; ++j)
#pragma unroll
        for (int r = 0; r < 4; ++r) {
          int t = w2 * 32 + i * 16 + quad * 4 + r;
          int s = j * 16 + lo;
          pm[cb + (u64)t * 64 + s] = f2b((s < t) ? ap[i][j][r] : 0.0f);
        }
  }
}

// ---------------------------------------------------------------------------
// sequential chunk recurrence, split 4-way over dv; gate fused at the store:
//   Uq = U0q + Wneg Sq^T ; Oq = sigmoid(G)*(Q Sq^T + P Uq) ; Sq += Uq^T K
// ---------------------------------------------------------------------------
__global__ __launch_bounds__(256) void chunk_seq(
    const u16* __restrict__ qn, const u16* __restrict__ kn,
    const u16* __restrict__ wneg, const u16* __restrict__ u0m,
    const u16* __restrict__ pm, const u16* __restrict__ gate,
    u16* __restrict__ ob)
{
  __shared__ __align__(16) u16 Qs[64 * LS], KTs[64 * LS], Ws[64 * LS], Ps[64 * LS];
  __shared__ __align__(16) u16 U0q[64 * 16];
  __shared__ __align__(16) u16 Sq[16 * LS], UTq[16 * LS];
  const int tid = threadIdx.x;
  const int lane = tid & 63, wave = tid >> 6;
  const int lo = lane & 15, quad = lane >> 4;
  const int blk = blockIdx.x;
  const int bh = blk >> 2, q = blk & 3;
  const int b = bh >> 4, h = bh & 15;
  f32x4 Sacc = {};

  for (int i = tid; i < 16 * LS; i += 256) Sq[i] = 0;
  __syncthreads();

#pragma unroll 1
  for (int c = 0; c < NCH; ++c) {
    const u64 gbase = ((u64)(b * TT + c * LCH) * HH + h) * DD;
    const u64 cb = (u64)(bh * NCH + c) * 4096;
#pragma unroll
    for (int it = 0; it < 2; ++it) {
      int idx = tid + it * 256;
      int t = idx >> 3, seg = (idx & 7) * 8;
      u64 g = gbase + (u64)t * CC + seg;
      *(u16x8*)(Qs + t * LS + seg) = *(const u16x8*)(qn + g);
      u16x8 kv = *(const u16x8*)(kn + g);
#pragma unroll
      for (int jj = 0; jj < 8; ++jj) KTs[(seg + jj) * LS + t] = kv[jj];
      *(u16x8*)(Ws + t * LS + seg) = *(const u16x8*)(wneg + cb + t * 64 + seg);
      *(u16x8*)(Ps + t * LS + seg) = *(const u16x8*)(pm + cb + t * 64 + seg);
    }
    if (tid < 128) {
      int t = tid >> 1, half = (tid & 1) * 8;
      *(u16x8*)(U0q + t * 16 + half) =
          *(const u16x8*)(u0m + cb + t * 64 + q * 16 + half);
    }
    __syncthreads();

    // Phase A: Uq[t, dv16] = U0q + Wneg * Sq^T  (wave = t-tile)
    f32x4 au;
#pragma unroll
    for (int r = 0; r < 4; ++r)
      au[r] = b2f(U0q[(wave * 16 + quad * 4 + r) * 16 + lo]);
#pragma unroll
    for (int k0 = 0; k0 < 64; k0 += 32) {
      bf16x8 af = ld8(Ws + (wave * 16 + lo) * LS + k0 + quad * 8);
      bf16x8 bq = ld8(Sq + lo * LS + k0 + quad * 8);
      au = MFMA16(af, bq, au);
    }
#pragma unroll
    for (int r = 0; r < 4; ++r)
      UTq[lo * LS + wave * 16 + quad * 4 + r] = f2b(au[r]);
    __syncthreads();

    // Phase B: Oq = Q Sq^T + P Uq
    f32x4 ao = {};
#pragma unroll
    for (int k0 = 0; k0 < 64; k0 += 32) {
      bf16x8 af = ld8(Qs + (wave * 16 + lo) * LS + k0 + quad * 8);
      bf16x8 bq = ld8(Sq + lo * LS + k0 + quad * 8);
      ao = MFMA16(af, bq, ao);
    }
#pragma unroll
    for (int k0 = 0; k0 < 64; k0 += 32) {
      bf16x8 af = ld8(Ps + (wave * 16 + lo) * LS + k0 + quad * 8);
      bf16x8 bq = ld8(UTq + lo * LS + k0 + quad * 8);
      ao = MFMA16(af, bq, ao);
    }
#pragma unroll
    for (int r = 0; r < 4; ++r) {
      u64 gidx = gbase + (u64)(wave * 16 + quad * 4 + r) * CC + q * 16 + lo;
      float gg = b2f(gate[gidx]);
      ob[gidx] = f2b(sigmoidf_(gg) * ao[r]);
    }

    // S update: Sq[dv, dk-tile wave] += Uq^T K
#pragma unroll
    for (int k0 = 0; k0 < 64; k0 += 32) {
      bf16x8 af = ld8(UTq + lo * LS + k0 + quad * 8);
      bf16x8 bq = ld8(KTs + (wave * 16 + lo) * LS + k0 + quad * 8);
      Sacc = MFMA16(af, bq, Sacc);
    }
    __syncthreads();
#pragma unroll
    for (int r = 0; r < 4; ++r)
      Sq[(quad * 4 + r) * LS + wave * 16 + lo] = f2b(Sacc[r]);
    __syncthreads();
  }
}

extern "C" void kernel_launch(void* const* d_in, const int* in_sizes, int n_in,
                              void* d_out, int out_size, void* d_ws, size_t ws_size,
                              hipStream_t stream)
{
  (void)in_sizes; (void)n_in; (void)out_size; (void)ws_size;
  const float* x32 = (const float*)d_in[0];
  char* ws = (char*)d_ws;
  const u64 SZ = (u64)BT * CC * 2;            // 16 MiB
  const u64 MB = 1ull << 20;

  u16* xn1  = (u16*)(ws + 0 * SZ);
  u16* qb   = (u16*)(ws + 1 * SZ);
  u16* kb   = (u16*)(ws + 2 * SZ);
  u16* vb   = (u16*)(ws + 3 * SZ);
  u16* grw  = (u16*)(ws + 4 * SZ);
  u16* wneg = (u16*)(ws + 5 * SZ);
  u16* u0m  = (u16*)(ws + 6 * SZ);
  u16* pmm  = (u16*)(ws + 7 * SZ);
  u16* obf  = (u16*)(ws + 8 * SZ);            // attn out; later aliased as xn2
  u16* x2   = (u16*)(ws + 9 * SZ);
  float* beta = (float*)(ws + 10 * SZ);       // 512 KiB
  char* CV  = ws + 10 * SZ + MB;              // canonical bf16 weights
  u16* qwc  = (u16*)(CV + 0 * MB);
  u16* kwc  = (u16*)(CV + 2 * MB);
  u16* vwc  = (u16*)(CV + 4 * MB);
  u16* gwc  = (u16*)(CV + 6 * MB);
  u16* owc  = (u16*)(CV + 8 * MB);
  u16* fgwc = (u16*)(CV + 10 * MB);
  u16* fuwc = (u16*)(CV + 18 * MB);
  u16* fdwc = (u16*)(CV + 26 * MB);
  u16* bwc  = (u16*)(CV + 34 * MB);
  u16* n1c  = (u16*)(CV + 34 * MB + 64 * 1024);
  u16* n2c  = (u16*)(CV + 34 * MB + 80 * 1024);
  u16* bbc  = (u16*)(CV + 34 * MB + 96 * 1024);
  u16* ffg  = (u16*)(ws + 0 * SZ);            // 64 MiB over xn1..vb (dead by then)
  u16* xn2  = obf;

  dim3 blk(256);
  dim3 g1(BT / 128, CC / 128);
  dim3 g2(BT / 128, FF / 128);

  CvtArgs ca;
  ca.d[0]  = { (const float*)d_in[5],  qwc,  (u32)(CC * CC), 0 };
  ca.d[1]  = { (const float*)d_in[6],  kwc,  (u32)(CC * CC), 0 };
  ca.d[2]  = { (const float*)d_in[7],  vwc,  (u32)(CC * CC), 0 };
  ca.d[3]  = { (const float*)d_in[10], gwc,  (u32)(CC * CC), 0 };
  ca.d[4]  = { (const float*)d_in[11], owc,  (u32)(CC * CC), 0 };
  ca.d[5]  = { (const float*)d_in[12], fgwc, (u32)(FF * CC), 0 };
  ca.d[6]  = { (const float*)d_in[13], fuwc, (u32)(FF * CC), 0 };
  ca.d[7]  = { (const float*)d_in[14], fdwc, (u32)(CC * FF), 0 };
  ca.d[8]  = { (const float*)d_in[8],  bwc,  (u32)(HH * CC), 0 };
  ca.d[9]  = { (const float*)d_in[3],  n1c,  (u32)CC, 0 };
  ca.d[10] = { (const float*)d_in[4],  n2c,  (u32)CC, 0 };
  ca.d[11] = { (const float*)d_in[9],  bbc,  (u32)HH, 0 };
  convert_k<<<dim3(2048, 12), blk, 0, stream>>>(ca);

  rmsnorm_k<1><<<BT, blk, 0, stream>>>(x32, n1c, xn1);
  gemm_bt<0><<<g1, blk, 0, stream>>>(xn1, qwc, qb, nullptr, BT, CC, CC);
  gemm_bt<0><<<g1, blk, 0, stream>>>(xn1, kwc, kb, nullptr, BT, CC, CC);
  gemm_bt<0><<<g1, blk, 0, stream>>>(xn1, vwc, vb, nullptr, BT, CC, CC);
  gemm_bt<0><<<g1, blk, 0, stream>>>(xn1, gwc, grw, nullptr, BT, CC, CC);
  beta_k<<<BT, blk, 0, stream>>>(xn1, bwc, bbc, beta);
  l2norm_k<<<BT, blk, 0, stream>>>(qb);
  l2norm_k<<<BT, blk, 0, stream>>>(kb);
  chunk_pre<<<BQ * HH * NCH, blk, 0, stream>>>(qb, kb, vb, beta, wneg, u0m, pmm);
  chunk_seq<<<BQ * HH * 4, blk, 0, stream>>>(qb, kb, wneg, u0m, pmm, grw, obf);
  gemm_bt<1><<<g1, blk, 0, stream>>>(obf, owc, x2, x32, BT, CC, CC);
  rmsnorm_k<0><<<BT, blk, 0, stream>>>(x2, n2c, xn2);
  gemm_bt<0><<<g2, blk, 0, stream>>>(xn2, fgwc, ffg, nullptr, BT, FF, CC);
  gemm_bt<3><<<g2, blk, 0, stream>>>(xn2, fuwc, ffg, ffg, BT, FF, CC);
  gemm_bt<2><<<g1, blk, 0, stream>>>(ffg, fdwc, d_out, x2, BT, CC, FF);
}

// Round 5
// 734.111 us; speedup vs baseline: 1.1460x; 1.0448x over previous
//
#include <hip/hip_runtime.h>
#include <stdint.h>

typedef unsigned short u16;
typedef unsigned int   u32;
typedef unsigned long long u64;

typedef __bf16 bf16x8 __attribute__((ext_vector_type(8)));
typedef u16    u16x8  __attribute__((ext_vector_type(8)));
typedef u16    u16x4  __attribute__((ext_vector_type(4)));
typedef float  f32x4  __attribute__((ext_vector_type(4)));

#define BQ 4
#define TT 2048
#define CC 1024
#define HH 16
#define DD 64
#define FF 4096
#define BT 8192      // B*T rows
#define NCH 32       // chunks per sequence
#define LCH 64       // chunk length
#define LS 72        // padded LDS stride for 64-wide tiles
#define SE 140       // epilogue LDS stride (u16)
#define FS 132       // epilogue LDS stride (f32)

__device__ __forceinline__ float b2f(u16 v) {
  u32 u = ((u32)v) << 16;
  return __builtin_bit_cast(float, u);
}
__device__ __forceinline__ u16 f2b(float f) {
  u32 u = __builtin_bit_cast(u32, f);
  u32 r = (u + 0x7fffu + ((u >> 16) & 1u)) >> 16;   // RNE
  return (u16)r;
}
__device__ __forceinline__ bf16x8 ld8(const u16* p) {
  return __builtin_bit_cast(bf16x8, *(const u16x8*)p);
}
__device__ __forceinline__ float sigmoidf_(float x) {
  return 1.0f / (1.0f + __expf(-x));
}

#define MFMA16(a, b, c) __builtin_amdgcn_mfma_f32_16x16x32_bf16(a, b, c, 0, 0, 0)

// async global->LDS, 16B/lane; HW writes lds_base + lane*16 (wave-uniform base)
__device__ __forceinline__ void stage16(const u16* g, u16* lds_base) {
  __builtin_amdgcn_global_load_lds(
      (const __attribute__((address_space(1))) u32*)(uintptr_t)g,
      (__attribute__((address_space(3))) u32*)lds_base, 16, 0, 0);
}

// fp32 -> bf16 weight canonicalization
struct Cvt { const float* src; u16* dst; u32 n; u32 pad; };
struct CvtArgs { Cvt d[12]; };

__global__ __launch_bounds__(256) void convert_k(CvtArgs a)
{
  const Cvt c = a.d[blockIdx.y];
  u64 i = ((u64)blockIdx.x * 256 + threadIdx.x) * 8;
  if (i >= c.n) return;
  f32x4 v0 = *(const f32x4*)(c.src + i);
  f32x4 v1 = *(const f32x4*)(c.src + i + 4);
  u16x8 o;
#pragma unroll
  for (int e = 0; e < 4; ++e) { o[e] = f2b(v0[e]); o[e + 4] = f2b(v1[e]); }
  *(u16x8*)(c.dst + i) = o;
}

// ---------------------------------------------------------------------------
// 128x128-tile bf16 bt-GEMM (kept for N=1024 outputs):
//   MODE 1: + fp32 residual, bf16 out (o-proj)
//   MODE 2: + bf16 residual, fp32 out, LDS-swizzled coalesced stores (down-proj)
// ---------------------------------------------------------------------------
template <int MODE>
__global__ __launch_bounds__(256) void gemm_bt(
    const u16* __restrict__ A, const u16* __restrict__ Bw,
    void* __restrict__ Cv, const void* __restrict__ res,
    int M, int N, int K)
{
  __shared__ __align__(16) u16 smem[128 * SE];   // 35840 B; staging uses 32 KiB
  const int tid  = threadIdx.x;
  const int lane = tid & 63;
  const int wave = tid >> 6;
  const int bm = blockIdx.x, bn = blockIdx.y;
  const int rw = lane >> 2;
  const int kq = (lane & 3) * 8;
  const int lo = lane & 15;
  const int quad = lane >> 4;
  const int wm = wave & 1, wn = wave >> 1;

  const u16* Ag = A  + (u64)(bm * 128 + wave * 16 + rw) * K + kq;
  const u16* Bg = Bw + (u64)(bn * 128 + wave * 16 + rw) * K + kq;
  u16* const Ab[2] = { smem + wave * 512, smem + 4096 + wave * 512 };
  u16* const Bb[2] = { smem + 8192 + wave * 512, smem + 12288 + wave * 512 };

  f32x4 acc[4][4] = {};
  const int niter = K >> 5;

  stage16(Ag, Ab[0]);
  stage16(Ag + (u64)64 * K, Ab[0] + 2048);
  stage16(Bg, Bb[0]);
  stage16(Bg + (u64)64 * K, Bb[0] + 2048);

  int cur = 0;
  for (int it = 0; it < niter; ++it) {
    __syncthreads();
    if (it + 1 < niter) {
      int kn = (it + 1) << 5;
      stage16(Ag + kn, Ab[cur ^ 1]);
      stage16(Ag + (u64)64 * K + kn, Ab[cur ^ 1] + 2048);
      stage16(Bg + kn, Bb[cur ^ 1]);
      stage16(Bg + (u64)64 * K + kn, Bb[cur ^ 1] + 2048);
    }
    const u16* Ac = smem + cur * 4096;
    const u16* Bc = smem + 8192 + cur * 4096;
    bf16x8 af[4], bq[4];
#pragma unroll
    for (int i = 0; i < 4; ++i)
      af[i] = ld8(Ac + (wm * 64 + i * 16 + lo) * 32 + quad * 8);
#pragma unroll
    for (int j = 0; j < 4; ++j)
      bq[j] = ld8(Bc + (wn * 64 + j * 16 + lo) * 32 + quad * 8);
#pragma unroll
    for (int i = 0; i < 4; ++i)
#pragma unroll
      for (int j = 0; j < 4; ++j)
        acc[i][j] = MFMA16(af[i], bq[j], acc[i][j]);
    cur ^= 1;
  }

  __syncthreads();
  if (MODE == 2) {
    // fp32 out + bf16 residual, via LDS swizzle in 2 half-passes of 64 rows
    float* Fsm = (float*)smem;                 // 64 x FS floats = 33792 B
    float* C32 = (float*)Cv;
    const u16* R16 = (const u16*)res;
#pragma unroll
    for (int hh = 0; hh < 2; ++hh) {
      if (wm == hh) {
#pragma unroll
        for (int i = 0; i < 4; ++i)
#pragma unroll
          for (int j = 0; j < 4; ++j)
#pragma unroll
            for (int r = 0; r < 4; ++r)
              Fsm[(i * 16 + quad * 4 + r) * FS + wn * 64 + j * 16 + lo] =
                  acc[i][j][r];
      }
      __syncthreads();
      const int r2 = tid >> 5, c2 = (tid & 31) * 4;
#pragma unroll
      for (int w = 0; w < 8; ++w) {
        int rl = r2 + w * 8;
        f32x4 v = *(const f32x4*)(Fsm + rl * FS + c2);
        u64 off = (u64)(bm * 128 + hh * 64 + rl) * N + bn * 128 + c2;
        u16x4 rr = *(const u16x4*)(R16 + off);
        f32x4 o;
#pragma unroll
        for (int e = 0; e < 4; ++e) o[e] = v[e] + b2f(rr[e]);
        *(f32x4*)(C32 + off) = o;
      }
      __syncthreads();
    }
    return;
  }

  // MODE 1: bf16 out + fp32 residual, swizzled epilogue
#pragma unroll
  for (int i = 0; i < 4; ++i)
#pragma unroll
    for (int j = 0; j < 4; ++j)
#pragma unroll
      for (int r = 0; r < 4; ++r)
        smem[(wm * 64 + i * 16 + quad * 4 + r) * SE + wn * 64 + j * 16 + lo] =
            f2b(acc[i][j][r]);
  __syncthreads();

  u16* C16 = (u16*)Cv;
  const float* R32 = (const float*)res;
  const int orow = tid >> 4, ocol = (tid & 15) * 8;
#pragma unroll
  for (int w = 0; w < 8; ++w) {
    int rl = orow + w * 16;
    u16x8 v = *(const u16x8*)(smem + rl * SE + ocol);
    u64 off = (u64)(bm * 128 + rl) * N + bn * 128 + ocol;
    f32x4 r0 = *(const f32x4*)(R32 + off);
    f32x4 r1 = *(const f32x4*)(R32 + off + 4);
    u16x8 o;
#pragma unroll
    for (int e = 0; e < 4; ++e) {
      o[e]     = f2b(b2f(v[e])     + r0[e]);
      o[e + 4] = f2b(b2f(v[e + 4]) + r1[e]);
    }
    *(u16x8*)(C16 + off) = o;
  }
}

// ---------------------------------------------------------------------------
// 256x128-tile bf16 bt-GEMM for N=4096 outputs. 4 waves, each 128x64.
//   MODE 0, SPLIT 0: plain bf16 out (FFN gate)
//   MODE 0, SPLIT 1: QKVG fused — output de-interleaved into 4 [BT,CC] buffers
//   MODE 3, SPLIT 0: out = silu(res)*acc (FFN up, in-place gate)
// ---------------------------------------------------------------------------
template <int MODE, int SPLIT>
__global__ __launch_bounds__(256, 2) void gemm_bt2(
    const u16* __restrict__ A, const u16* __restrict__ Bw,
    u16* __restrict__ C, const u16* __restrict__ res,
    int M, int N, int K)
{
  __shared__ __align__(16) u16 smem[24576];   // A:2x8192 | B:2x4096 u16 = 48 KiB
  const int tid  = threadIdx.x;
  const int lane = tid & 63;
  const int wave = tid >> 6;
  const int bm = blockIdx.x, bn = blockIdx.y;
  const int rw = lane >> 2;
  const int kq = (lane & 3) * 8;
  const int lo = lane & 15;
  const int quad = lane >> 4;
  const int wm = wave & 1, wn = wave >> 1;

  const u16* Ag = A  + (u64)(bm * 256 + wave * 16 + rw) * K + kq;
  const u16* Bg = Bw + (u64)(bn * 128 + wave * 16 + rw) * K + kq;
  u16* const Ab[2] = { smem + wave * 512, smem + 8192 + wave * 512 };
  u16* const Bb[2] = { smem + 16384 + wave * 512, smem + 20480 + wave * 512 };

  f32x4 acc[8][4] = {};
  const int niter = K >> 5;

#pragma unroll
  for (int r = 0; r < 4; ++r) stage16(Ag + (u64)(64 * r) * K, Ab[0] + r * 2048);
#pragma unroll
  for (int r = 0; r < 2; ++r) stage16(Bg + (u64)(64 * r) * K, Bb[0] + r * 2048);

  int cur = 0;
  for (int it = 0; it < niter; ++it) {
    __syncthreads();
    if (it + 1 < niter) {
      int kn = (it + 1) << 5;
#pragma unroll
      for (int r = 0; r < 4; ++r)
        stage16(Ag + (u64)(64 * r) * K + kn, Ab[cur ^ 1] + r * 2048);
#pragma unroll
      for (int r = 0; r < 2; ++r)
        stage16(Bg + (u64)(64 * r) * K + kn, Bb[cur ^ 1] + r * 2048);
    }
    const u16* Ac = smem + cur * 8192;
    const u16* Bc = smem + 16384 + cur * 4096;
    bf16x8 af[8], bq[4];
#pragma unroll
    for (int i = 0; i < 8; ++i)
      af[i] = ld8(Ac + (wm * 128 + i * 16 + lo) * 32 + quad * 8);
#pragma unroll
    for (int j = 0; j < 4; ++j)
      bq[j] = ld8(Bc + (wn * 64 + j * 16 + lo) * 32 + quad * 8);
#pragma unroll
    for (int i = 0; i < 8; ++i)
#pragma unroll
      for (int j = 0; j < 4; ++j)
        acc[i][j] = MFMA16(af[i], bq[j], acc[i][j]);
    cur ^= 1;
  }

  // epilogue: two half-passes of 128 rows through LDS (stride SE)
  __syncthreads();
  const int orow = tid >> 4, ocol = (tid & 15) * 8;
#pragma unroll
  for (int hh = 0; hh < 2; ++hh) {
    if (wm == hh) {
#pragma unroll
      for (int i = 0; i < 8; ++i)
#pragma unroll
        for (int j = 0; j < 4; ++j)
#pragma unroll
          for (int r = 0; r < 4; ++r)
            smem[(i * 16 + quad * 4 + r) * SE + wn * 64 + j * 16 + lo] =
                f2b(acc[i][j][r]);
    }
    __syncthreads();
#pragma unroll
    for (int w = 0; w < 8; ++w) {
      int rl = orow + w * 16;
      int row = bm * 256 + hh * 128 + rl;
      u16x8 v = *(const u16x8*)(smem + rl * SE + ocol);
      if (SPLIT) {
        int proj = bn >> 3;
        int colp = (bn & 7) * 128 + ocol;
        *(u16x8*)(C + (u64)proj * BT * CC + (u64)row * CC + colp) = v;
      } else {
        u64 off = (u64)row * N + bn * 128 + ocol;
        if (MODE == 3) {
          u16x8 g = *(const u16x8*)(res + off);
          u16x8 o;
#pragma unroll
          for (int e = 0; e < 8; ++e) {
            float gg = b2f(g[e]);
            o[e] = f2b(gg * sigmoidf_(gg) * b2f(v[e]));
          }
          *(u16x8*)(C + off) = o;
        } else {
          *(u16x8*)(C + off) = v;
        }
      }
    }
    __syncthreads();
  }
}

// ---------------------------------------------------------------------------
// rmsnorm: fp32/bf16 in, bf16 out
// ---------------------------------------------------------------------------
template <int IN32>
__global__ __launch_bounds__(256) void rmsnorm_k(
    const void* __restrict__ xv, const u16* __restrict__ w, u16* __restrict__ out)
{
  __shared__ float red[4];
  const int row = blockIdx.x, tid = threadIdx.x;
  float v0, v1, v2, v3;
  if (IN32) {
    f32x4 raw = *(const f32x4*)((const float*)xv + (u64)row * CC + tid * 4);
    v0 = raw[0]; v1 = raw[1]; v2 = raw[2]; v3 = raw[3];
  } else {
    u16x4 raw = *(const u16x4*)((const u16*)xv + (u64)row * CC + tid * 4);
    v0 = b2f(raw[0]); v1 = b2f(raw[1]); v2 = b2f(raw[2]); v3 = b2f(raw[3]);
  }
  float s = v0 * v0 + v1 * v1 + v2 * v2 + v3 * v3;
#pragma unroll
  for (int m = 1; m < 64; m <<= 1) s += __shfl_xor(s, m, 64);
  if ((tid & 63) == 0) red[tid >> 6] = s;
  __syncthreads();
  float tot = red[0] + red[1] + red[2] + red[3];
  float r = rsqrtf(tot * (1.0f / CC) + 1e-6f);
  const u16* wr = w + tid * 4;
  u16x4 o;
  o[0] = f2b(v0 * r * b2f(wr[0]));
  o[1] = f2b(v1 * r * b2f(wr[1]));
  o[2] = f2b(v2 * r * b2f(wr[2]));
  o[3] = f2b(v3 * r * b2f(wr[3]));
  *(u16x4*)(out + (u64)row * CC + tid * 4) = o;
}

// per-head l2 normalize in place
__global__ __launch_bounds__(256) void l2norm_k(u16* __restrict__ q)
{
  const int row = blockIdx.x, tid = threadIdx.x;
  const int hh = tid >> 4, ss = tid & 15;
  u16* p = q + (u64)row * CC + hh * DD + ss * 4;
  u16x4 raw = *(const u16x4*)p;
  float v0 = b2f(raw[0]), v1 = b2f(raw[1]), v2 = b2f(raw[2]), v3 = b2f(raw[3]);
  float s = v0 * v0 + v1 * v1 + v2 * v2 + v3 * v3;
#pragma unroll
  for (int m = 1; m < 16; m <<= 1) s += __shfl_xor(s, m, 64);
  float sc = 1.0f / fmaxf(sqrtf(s), 1e-12f);
  u16x4 o;
  o[0] = f2b(v0 * sc); o[1] = f2b(v1 * sc);
  o[2] = f2b(v2 * sc); o[3] = f2b(v3 * sc);
  *(u16x4*)p = o;
}

// beta = sigmoid(xn @ bw^T + bb)
__global__ __launch_bounds__(256) void beta_k(
    const u16* __restrict__ xn, const u16* __restrict__ bw,
    const u16* __restrict__ bb, float* __restrict__ beta)
{
  const int row = blockIdx.x, tid = threadIdx.x;
  const int hh = tid >> 4, ss = tid & 15;
  const u16* xr = xn + (u64)row * CC + ss * 64;
  const u16* wr = bw + (u64)hh * CC + ss * 64;
  float s = 0.f;
#pragma unroll
  for (int j = 0; j < 8; ++j) {
    u16x8 a = *(const u16x8*)(xr + j * 8);
    u16x8 c = *(const u16x8*)(wr + j * 8);
#pragma unroll
    for (int e = 0; e < 8; ++e) s += b2f(a[e]) * b2f(c[e]);
  }
#pragma unroll
  for (int m = 1; m < 16; m <<= 1) s += __shfl_xor(s, m, 64);
  if (ss == 0) beta[(u64)row * HH + hh] = sigmoidf_(s + b2f(bb[hh]));
}

// ---------------------------------------------------------------------------
// chunk precompute (parallel over b,h,chunk)
// ---------------------------------------------------------------------------
__global__ __launch_bounds__(256) void chunk_pre(
    const u16* __restrict__ qn, const u16* __restrict__ kn,
    const u16* __restrict__ vn, const float* __restrict__ beta,
    u16* __restrict__ wneg, u16* __restrict__ u0m, u16* __restrict__ pm)
{
  __shared__ __align__(16) u16 Qc[64 * LS], Kc[64 * LS], Vc[64 * LS];
  __shared__ float Af[64 * 64];
  __shared__ float bet[64];
  const int tid = threadIdx.x;
  const int lane = tid & 63, wave = tid >> 6;
  const int lo = lane & 15, quad = lane >> 4;
  const int bc = blockIdx.x;
  const int bh = bc >> 5, c = bc & 31;
  const int b = bh >> 4, h = bh & 15;
  const u64 gbase = ((u64)(b * TT + c * LCH) * HH + h) * DD;
  const u64 cb = (u64)bc * 4096;

#pragma unroll
  for (int it = 0; it < 2; ++it) {
    int idx = tid + it * 256;
    int t = idx >> 3, seg = (idx & 7) * 8;
    u64 g = gbase + (u64)t * CC + seg;
    *(u16x8*)(Qc + t * LS + seg) = *(const u16x8*)(qn + g);
    *(u16x8*)(Kc + t * LS + seg) = *(const u16x8*)(kn + g);
    *(u16x8*)(Vc + t * LS + seg) = *(const u16x8*)(vn + g);
  }
  if (tid < 64) bet[tid] = beta[(u64)(b * TT + c * LCH + tid) * HH + h];
  __syncthreads();

  { // A = strict_tril(diag(beta) K K^T)
    const int wm = wave & 1, wn = wave >> 1;
    f32x4 aa[2][2] = {};
#pragma unroll
    for (int k0 = 0; k0 < 64; k0 += 32) {
      bf16x8 af[2], bq[2];
#pragma unroll
      for (int i = 0; i < 2; ++i) af[i] = ld8(Kc + (wm * 32 + i * 16 + lo) * LS + k0 + quad * 8);
#pragma unroll
      for (int j = 0; j < 2; ++j) bq[j] = ld8(Kc + (wn * 32 + j * 16 + lo) * LS + k0 + quad * 8);
#pragma unroll
      for (int i = 0; i < 2; ++i)
#pragma unroll
        for (int j = 0; j < 2; ++j) aa[i][j] = MFMA16(af[i], bq[j], aa[i][j]);
    }
#pragma unroll
    for (int i = 0; i < 2; ++i)
#pragma unroll
      for (int j = 0; j < 2; ++j)
#pragma unroll
        for (int r = 0; r < 4; ++r) {
          int t = wm * 32 + i * 16 + quad * 4 + r;
          int s = wn * 32 + j * 16 + lo;
          Af[t * 64 + s] = (s < t) ? bet[t] * aa[i][j][r] : 0.0f;
        }
  }
  __syncthreads();

  if (wave < 2) {
    // forward substitution of (I+A); lane = column d
    const u16* src = (wave == 0) ? Kc : Vc;
    u16* dst = (wave == 0) ? wneg : u0m;
    const float sgn = (wave == 0) ? -1.0f : 1.0f;
    const int d = lane;
    float hist[64];
#pragma unroll
    for (int t = 0; t < 64; ++t) {
      float a = bet[t] * b2f(src[t * LS + d]);
#pragma unroll
      for (int s = 0; s < t; ++s) a -= Af[t * 64 + s] * hist[s];
      hist[t] = a;
      dst[cb + (u64)t * 64 + d] = f2b(sgn * a);
    }
  } else {
    // P = strict_tril(Q K^T)
    const int w2 = wave - 2;
    f32x4 ap[2][4] = {};
#pragma unroll
    for (int k0 = 0; k0 < 64; k0 += 32) {
      bf16x8 af[2], bq[4];
#pragma unroll
      for (int i = 0; i < 2; ++i) af[i] = ld8(Qc + (w2 * 32 + i * 16 + lo) * LS + k0 + quad * 8);
#pragma unroll
      for (int j = 0; j < 4; ++j) bq[j] = ld8(Kc + (j * 16 + lo) * LS + k0 + quad * 8);
#pragma unroll
      for (int i = 0; i < 2; ++i)
#pragma unroll
        for (int j = 0; j < 4; ++j) ap[i][j] = MFMA16(af[i], bq[j], ap[i][j]);
    }
#pragma unroll
    for (int i = 0; i < 2; ++i)
#pragma unroll
      for (int j = 0; j < 4; ++j)
#pragma unroll
        for (int r = 0; r < 4; ++r) {
          int t = w2 * 32 + i * 16 + quad * 4 + r;
          int s = j * 16 + lo;
          pm[cb + (u64)t * 64 + s] = f2b((s < t) ? ap[i][j][r] : 0.0f);
        }
  }
}

// ---------------------------------------------------------------------------
// sequential chunk recurrence, split 4-way over dv; gate fused at the store
// ---------------------------------------------------------------------------
__global__ __launch_bounds__(256) void chunk_seq(
    const u16* __restrict__ qn, const u16* __restrict__ kn,
    const u16* __restrict__ wneg, const u16* __restrict__ u0m,
    const u16* __restrict__ pm, const u16* __restrict__ gate,
    u16* __restrict__ ob)
{
  __shared__ __align__(16) u16 Qs[64 * LS], KTs[64 * LS], Ws[64 * LS], Ps[64 * LS];
  __shared__ __align__(16) u16 U0q[64 * 16];
  __shared__ __align__(16) u16 Sq[16 * LS], UTq[16 * LS];
  const int tid = threadIdx.x;
  const int lane = tid & 63, wave = tid >> 6;
  const int lo = lane & 15, quad = lane >> 4;
  const int blk = blockIdx.x;
  const int bh = blk >> 2, q = blk & 3;
  const int b = bh >> 4, h = bh & 15;
  f32x4 Sacc = {};

  for (int i = tid; i < 16 * LS; i += 256) Sq[i] = 0;
  __syncthreads();

#pragma unroll 1
  for (int c = 0; c < NCH; ++c) {
    const u64 gbase = ((u64)(b * TT + c * LCH) * HH + h) * DD;
    const u64 cb = (u64)(bh * NCH + c) * 4096;
#pragma unroll
    for (int it = 0; it < 2; ++it) {
      int idx = tid + it * 256;
      int t = idx >> 3, seg = (idx & 7) * 8;
      u64 g = gbase + (u64)t * CC + seg;
      *(u16x8*)(Qs + t * LS + seg) = *(const u16x8*)(qn + g);
      u16x8 kv = *(const u16x8*)(kn + g);
#pragma unroll
      for (int jj = 0; jj < 8; ++jj) KTs[(seg + jj) * LS + t] = kv[jj];
      *(u16x8*)(Ws + t * LS + seg) = *(const u16x8*)(wneg + cb + t * 64 + seg);
      *(u16x8*)(Ps + t * LS + seg) = *(const u16x8*)(pm + cb + t * 64 + seg);
    }
    if (tid < 128) {
      int t = tid >> 1, half = (tid & 1) * 8;
      *(u16x8*)(U0q + t * 16 + half) =
          *(const u16x8*)(u0m + cb + t * 64 + q * 16 + half);
    }
    __syncthreads();

    // Phase A: Uq[t, dv16] = U0q + Wneg * Sq^T
    f32x4 au;
#pragma unroll
    for (int r = 0; r < 4; ++r)
      au[r] = b2f(U0q[(wave * 16 + quad * 4 + r) * 16 + lo]);
#pragma unroll
    for (int k0 = 0; k0 < 64; k0 += 32) {
      bf16x8 af = ld8(Ws + (wave * 16 + lo) * LS + k0 + quad * 8);
      bf16x8 bq = ld8(Sq + lo * LS + k0 + quad * 8);
      au = MFMA16(af, bq, au);
    }
#pragma unroll
    for (int r = 0; r < 4; ++r)
      UTq[lo * LS + wave * 16 + quad * 4 + r] = f2b(au[r]);
    __syncthreads();

    // Phase B: Oq = Q Sq^T + P Uq, gated store
    f32x4 ao = {};
#pragma unroll
    for (int k0 = 0; k0 < 64; k0 += 32) {
      bf16x8 af = ld8(Qs + (wave * 16 + lo) * LS + k0 + quad * 8);
      bf16x8 bq = ld8(Sq + lo * LS + k0 + quad * 8);
      ao = MFMA16(af, bq, ao);
    }
#pragma unroll
    for (int k0 = 0; k0 < 64; k0 += 32) {
      bf16x8 af = ld8(Ps + (wave * 16 + lo) * LS + k0 + quad * 8);
      bf16x8 bq = ld8(UTq + lo * LS + k0 + quad * 8);
      ao = MFMA16(af, bq, ao);
    }
#pragma unroll
    for (int r = 0; r < 4; ++r) {
      u64 gidx = gbase + (u64)(wave * 16 + quad * 4 + r) * CC + q * 16 + lo;
      float gg = b2f(gate[gidx]);
      ob[gidx] = f2b(sigmoidf_(gg) * ao[r]);
    }

    // S update: Sq += Uq^T K
#pragma unroll
    for (int k0 = 0; k0 < 64; k0 += 32) {
      bf16x8 af = ld8(UTq + lo * LS + k0 + quad * 8);
      bf16x8 bq = ld8(KTs + (wave * 16 + lo) * LS + k0 + quad * 8);
      Sacc = MFMA16(af, bq, Sacc);
    }
    __syncthreads();
#pragma unroll
    for (int r = 0; r < 4; ++r)
      Sq[(quad * 4 + r) * LS + wave * 16 + lo] = f2b(Sacc[r]);
    __syncthreads();
  }
}

extern "C" void kernel_launch(void* const* d_in, const int* in_sizes, int n_in,
                              void* d_out, int out_size, void* d_ws, size_t ws_size,
                              hipStream_t stream)
{
  (void)in_sizes; (void)n_in; (void)out_size; (void)ws_size;
  const float* x32 = (const float*)d_in[0];
  char* ws = (char*)d_ws;
  const u64 SZ = (u64)BT * CC * 2;            // 16 MiB
  const u64 MB = 1ull << 20;

  u16* xn1  = (u16*)(ws + 0 * SZ);
  u16* qb   = (u16*)(ws + 1 * SZ);            // qb,kb,vb,grw contiguous (QKVG dst)
  u16* kb   = (u16*)(ws + 2 * SZ);
  u16* vb   = (u16*)(ws + 3 * SZ);
  u16* grw  = (u16*)(ws + 4 * SZ);
  u16* wneg = (u16*)(ws + 5 * SZ);
  u16* u0m  = (u16*)(ws + 6 * SZ);
  u16* pmm  = (u16*)(ws + 7 * SZ);
  u16* obf  = (u16*)(ws + 8 * SZ);            // attn out; later aliased as xn2
  u16* x2   = (u16*)(ws + 9 * SZ);
  float* beta = (float*)(ws + 10 * SZ);       // 512 KiB
  char* CV  = ws + 10 * SZ + MB;              // canonical bf16 weights
  u16* qwc  = (u16*)(CV + 0 * MB);            // qwc..gwc contiguous [4096,1024]
  u16* kwc  = (u16*)(CV + 2 * MB);
  u16* vwc  = (u16*)(CV + 4 * MB);
  u16* gwc  = (u16*)(CV + 6 * MB);
  u16* owc  = (u16*)(CV + 8 * MB);
  u16* fgwc = (u16*)(CV + 10 * MB);
  u16* fuwc = (u16*)(CV + 18 * MB);
  u16* fdwc = (u16*)(CV + 26 * MB);
  u16* bwc  = (u16*)(CV + 34 * MB);
  u16* n1c  = (u16*)(CV + 34 * MB + 64 * 1024);
  u16* n2c  = (u16*)(CV + 34 * MB + 80 * 1024);
  u16* bbc  = (u16*)(CV + 34 * MB + 96 * 1024);
  u16* ffg  = (u16*)(ws + 0 * SZ);            // 64 MiB over xn1..vb (dead by then)
  u16* xn2  = obf;

  dim3 blk(256);
  dim3 g1(BT / 128, CC / 128);                // 128x128 kernels
  dim3 g2(BT / 256, FF / 128);                // 256x128 kernels (N=4096)

  CvtArgs ca;
  ca.d[0]  = { (const float*)d_in[5],  qwc,  (u32)(CC * CC), 0 };
  ca.d[1]  = { (const float*)d_in[6],  kwc,  (u32)(CC * CC), 0 };
  ca.d[2]  = { (const float*)d_in[7],  vwc,  (u32)(CC * CC), 0 };
  ca.d[3]  = { (const float*)d_in[10], gwc,  (u32)(CC * CC), 0 };
  ca.d[4]  = { (const float*)d_in[11], owc,  (u32)(CC * CC), 0 };
  ca.d[5]  = { (const float*)d_in[12], fgwc, (u32)(FF * CC), 0 };
  ca.d[6]  = { (const float*)d_in[13], fuwc, (u32)(FF * CC), 0 };
  ca.d[7]  = { (const float*)d_in[14], fdwc, (u32)(CC * FF), 0 };
  ca.d[8]  = { (const float*)d_in[8],  bwc,  (u32)(HH * CC), 0 };
  ca.d[9]  = { (const float*)d_in[3],  n1c,  (u32)CC, 0 };
  ca.d[10] = { (const float*)d_in[4],  n2c,  (u32)CC, 0 };
  ca.d[11] = { (const float*)d_in[9],  bbc,  (u32)HH, 0 };
  convert_k<<<dim3(2048, 12), blk, 0, stream>>>(ca);

  rmsnorm_k<1><<<BT, blk, 0, stream>>>(x32, n1c, xn1);
  // QKVG fused: one 8192x4096x1024 GEMM, de-interleaved into qb/kb/vb/grw
  gemm_bt2<0, 1><<<g2, blk, 0, stream>>>(xn1, qwc, qb, nullptr, BT, FF, CC);
  beta_k<<<BT, blk, 0, stream>>>(xn1, bwc, bbc, beta);
  l2norm_k<<<BT, blk, 0, stream>>>(qb);
  l2norm_k<<<BT, blk, 0, stream>>>(kb);
  chunk_pre<<<BQ * HH * NCH, blk, 0, stream>>>(qb, kb, vb, beta, wneg, u0m, pmm);
  chunk_seq<<<BQ * HH * 4, blk, 0, stream>>>(qb, kb, wneg, u0m, pmm, grw, obf);
  gemm_bt<1><<<g1, blk, 0, stream>>>(obf, owc, x2, x32, BT, CC, CC);
  rmsnorm_k<0><<<BT, blk, 0, stream>>>(x2, n2c, xn2);
  gemm_bt2<0, 0><<<g2, blk, 0, stream>>>(xn2, fgwc, ffg, nullptr, BT, FF, CC);
  gemm_bt2<3, 0><<<g2, blk, 0, stream>>>(xn2, fuwc, ffg, ffg, BT, FF, CC);
  gemm_bt<2><<<g1, blk, 0, stream>>>(ffg, fdwc, d_out, x2, BT, CC, FF);
}

// Round 6
// 711.635 us; speedup vs baseline: 1.1822x; 1.0316x over previous
//
#include <hip/hip_runtime.h>
#include <stdint.h>

typedef unsigned short u16;
typedef unsigned int   u32;
typedef unsigned long long u64;

typedef __bf16 bf16x8 __attribute__((ext_vector_type(8)));
typedef u16    u16x8  __attribute__((ext_vector_type(8)));
typedef u16    u16x4  __attribute__((ext_vector_type(4)));
typedef float  f32x4  __attribute__((ext_vector_type(4)));

#define BQ 4
#define TT 2048
#define CC 1024
#define HH 16
#define DD 64
#define FF 4096
#define BT 8192      // B*T rows
#define NCH 32       // chunks per sequence
#define LCH 64       // chunk length
#define LS 72        // padded LDS stride for 64-wide tiles
#define SE 140       // epilogue LDS stride (u16)
#define FS 132       // epilogue LDS stride (f32)

__device__ __forceinline__ float b2f(u16 v) {
  u32 u = ((u32)v) << 16;
  return __builtin_bit_cast(float, u);
}
__device__ __forceinline__ u16 f2b(float f) {
  u32 u = __builtin_bit_cast(u32, f);
  u32 r = (u + 0x7fffu + ((u >> 16) & 1u)) >> 16;   // RNE
  return (u16)r;
}
__device__ __forceinline__ bf16x8 ld8(const u16* p) {
  return __builtin_bit_cast(bf16x8, *(const u16x8*)p);
}
__device__ __forceinline__ float sigmoidf_(float x) {
  return 1.0f / (1.0f + __expf(-x));
}

#define MFMA16(a, b, c) __builtin_amdgcn_mfma_f32_16x16x32_bf16(a, b, c, 0, 0, 0)

// async global->LDS, 16B/lane; HW writes lds_base + lane*16 (wave-uniform base)
__device__ __forceinline__ void stage16(const u16* g, u16* lds_base) {
  __builtin_amdgcn_global_load_lds(
      (const __attribute__((address_space(1))) u32*)(uintptr_t)g,
      (__attribute__((address_space(3))) u32*)lds_base, 16, 0, 0);
}

// barrier that keeps up to N vector loads in flight (AITER-style; never vmcnt(0)
// mid-loop). Each wave waits only for its OLDEST (outstanding-N) loads.
#define BAR_VM(N) asm volatile("s_waitcnt vmcnt(" #N ")\n\ts_barrier" ::: "memory")

// fp32 -> bf16 weight canonicalization
struct Cvt { const float* src; u16* dst; u32 n; u32 pad; };
struct CvtArgs { Cvt d[12]; };

__global__ __launch_bounds__(256) void convert_k(CvtArgs a)
{
  const Cvt c = a.d[blockIdx.y];
  u64 i = ((u64)blockIdx.x * 256 + threadIdx.x) * 8;
  if (i >= c.n) return;
  f32x4 v0 = *(const f32x4*)(c.src + i);
  f32x4 v1 = *(const f32x4*)(c.src + i + 4);
  u16x8 o;
#pragma unroll
  for (int e = 0; e < 4; ++e) { o[e] = f2b(v0[e]); o[e + 4] = f2b(v1[e]); }
  *(u16x8*)(c.dst + i) = o;
}

// ---------------------------------------------------------------------------
// 128x128-tile bf16 bt-GEMM, 3-stage pipelined K-loop (N=1024 outputs):
//   MODE 1: + fp32 residual, bf16 out (o-proj)
//   MODE 2: + bf16 residual, fp32 out, coalesced stores (down-proj)
// Per stage: A 4096 u16 | B 4096 u16. 3 stages = 48 KiB.
// ---------------------------------------------------------------------------
template <int MODE>
__global__ __launch_bounds__(256, 3) void gemm_bt(
    const u16* __restrict__ A, const u16* __restrict__ Bw,
    void* __restrict__ Cv, const void* __restrict__ res,
    int M, int N, int K)
{
  __shared__ __align__(16) u16 smem[24576];   // 48 KiB
  const int tid  = threadIdx.x;
  const int lane = tid & 63;
  const int wave = tid >> 6;
  const int bm = blockIdx.x, bn = blockIdx.y;
  const int lo = lane & 15;
  const int quad = lane >> 4;
  const int wm = wave & 1, wn = wave >> 1;

  const int rw = lane >> 2;
  const int kq = (lane & 3) * 8;
  const u16* Ag = A  + (u64)(bm * 128 + wave * 16 + rw) * K + kq;
  const u16* Bg = Bw + (u64)(bn * 128 + wave * 16 + rw) * K + kq;

  f32x4 acc[4][4] = {};
  const int niter = K >> 5;

  // stage tile t into slot s (4 loads/wave)
  auto stage = [&](int t, int s) {
    int kk = t << 5;
    u16* base = smem + s * 8192;
    stage16(Ag + kk,                 base + wave * 512);
    stage16(Ag + (u64)64 * K + kk,   base + 2048 + wave * 512);
    stage16(Bg + kk,                 base + 4096 + wave * 512);
    stage16(Bg + (u64)64 * K + kk,   base + 4096 + 2048 + wave * 512);
  };

  stage(0, 0);
  stage(1, 1);

  int sc = 0, sp = 2;
  for (int it = 0; it < niter; ++it) {
    if (it + 1 < niter) BAR_VM(4);    // keep tile it+1 (4 loads) in flight
    else BAR_VM(0);
    if (it + 2 < niter) stage(it + 2, sp);
    const u16* Ac = smem + sc * 8192;
    const u16* Bc = Ac + 4096;
    bf16x8 af[4], bq[4];
#pragma unroll
    for (int i = 0; i < 4; ++i)
      af[i] = ld8(Ac + (wm * 64 + i * 16 + lo) * 32 + quad * 8);
#pragma unroll
    for (int j = 0; j < 4; ++j)
      bq[j] = ld8(Bc + (wn * 64 + j * 16 + lo) * 32 + quad * 8);
#pragma unroll
    for (int i = 0; i < 4; ++i)
#pragma unroll
      for (int j = 0; j < 4; ++j)
        acc[i][j] = MFMA16(af[i], bq[j], acc[i][j]);
    sc = (sc == 2) ? 0 : sc + 1;
    sp = (sp == 2) ? 0 : sp + 1;
  }

  __syncthreads();
  if (MODE == 2) {
    // fp32 out + bf16 residual, via LDS swizzle in 2 half-passes of 64 rows
    float* Fsm = (float*)smem;                 // 64 x FS floats = 33792 B
    float* C32 = (float*)Cv;
    const u16* R16 = (const u16*)res;
#pragma unroll
    for (int hh = 0; hh < 2; ++hh) {
      if (wm == hh) {
#pragma unroll
        for (int i = 0; i < 4; ++i)
#pragma unroll
          for (int j = 0; j < 4; ++j)
#pragma unroll
            for (int r = 0; r < 4; ++r)
              Fsm[(i * 16 + quad * 4 + r) * FS + wn * 64 + j * 16 + lo] =
                  acc[i][j][r];
      }
      __syncthreads();
      const int r2 = tid >> 5, c2 = (tid & 31) * 4;
#pragma unroll
      for (int w = 0; w < 8; ++w) {
        int rl = r2 + w * 8;
        f32x4 v = *(const f32x4*)(Fsm + rl * FS + c2);
        u64 off = (u64)(bm * 128 + hh * 64 + rl) * N + bn * 128 + c2;
        u16x4 rr = *(const u16x4*)(R16 + off);
        f32x4 o;
#pragma unroll
        for (int e = 0; e < 4; ++e) o[e] = v[e] + b2f(rr[e]);
        *(f32x4*)(C32 + off) = o;
      }
      __syncthreads();
    }
    return;
  }

  // MODE 1: bf16 out + fp32 residual, swizzled epilogue
#pragma unroll
  for (int i = 0; i < 4; ++i)
#pragma unroll
    for (int j = 0; j < 4; ++j)
#pragma unroll
      for (int r = 0; r < 4; ++r)
        smem[(wm * 64 + i * 16 + quad * 4 + r) * SE + wn * 64 + j * 16 + lo] =
            f2b(acc[i][j][r]);
  __syncthreads();

  u16* C16 = (u16*)Cv;
  const float* R32 = (const float*)res;
  const int orow = tid >> 4, ocol = (tid & 15) * 8;
#pragma unroll
  for (int w = 0; w < 8; ++w) {
    int rl = orow + w * 16;
    u16x8 v = *(const u16x8*)(smem + rl * SE + ocol);
    u64 off = (u64)(bm * 128 + rl) * N + bn * 128 + ocol;
    f32x4 r0 = *(const f32x4*)(R32 + off);
    f32x4 r1 = *(const f32x4*)(R32 + off + 4);
    u16x8 o;
#pragma unroll
    for (int e = 0; e < 4; ++e) {
      o[e]     = f2b(b2f(v[e])     + r0[e]);
      o[e + 4] = f2b(b2f(v[e + 4]) + r1[e]);
    }
    *(u16x8*)(C16 + off) = o;
  }
}

// ---------------------------------------------------------------------------
// 256x128-tile bf16 bt-GEMM, 3-stage pipelined K-loop (N=4096 outputs).
//   MODE 0, SPLIT 0: plain bf16 out (FFN gate)
//   MODE 0, SPLIT 1: QKVG fused — de-interleaved into 4 [BT,CC] buffers
//   MODE 3, SPLIT 0: out = silu(res)*acc (FFN up, in-place gate)
// Per stage: A 8192 u16 | B 4096 u16. 3 stages = 72 KiB.
// ---------------------------------------------------------------------------
template <int MODE, int SPLIT>
__global__ __launch_bounds__(256, 2) void gemm_bt2(
    const u16* __restrict__ A, const u16* __restrict__ Bw,
    u16* __restrict__ C, const u16* __restrict__ res,
    int M, int N, int K)
{
  __shared__ __align__(16) u16 smem[36864];   // 72 KiB
  const int tid  = threadIdx.x;
  const int lane = tid & 63;
  const int wave = tid >> 6;
  const int bm = blockIdx.x, bn = blockIdx.y;
  const int lo = lane & 15;
  const int quad = lane >> 4;
  const int wm = wave & 1, wn = wave >> 1;

  const int rw = lane >> 2;
  const int kq = (lane & 3) * 8;
  const u16* Ag = A  + (u64)(bm * 256 + wave * 16 + rw) * K + kq;
  const u16* Bg = Bw + (u64)(bn * 128 + wave * 16 + rw) * K + kq;

  f32x4 acc[8][4] = {};
  const int niter = K >> 5;

  auto stage = [&](int t, int s) {
    int kk = t << 5;
    u16* base = smem + s * 12288;
#pragma unroll
    for (int r = 0; r < 4; ++r)
      stage16(Ag + (u64)(64 * r) * K + kk, base + r * 2048 + wave * 512);
#pragma unroll
    for (int r = 0; r < 2; ++r)
      stage16(Bg + (u64)(64 * r) * K + kk, base + 8192 + r * 2048 + wave * 512);
  };

  stage(0, 0);
  stage(1, 1);

  int sc = 0, sp = 2;
  for (int it = 0; it < niter; ++it) {
    if (it + 1 < niter) BAR_VM(6);    // keep tile it+1 (6 loads) in flight
    else BAR_VM(0);
    if (it + 2 < niter) stage(it + 2, sp);
    const u16* Ac = smem + sc * 12288;
    const u16* Bc = Ac + 8192;
    bf16x8 af[8], bq[4];
#pragma unroll
    for (int i = 0; i < 8; ++i)
      af[i] = ld8(Ac + (wm * 128 + i * 16 + lo) * 32 + quad * 8);
#pragma unroll
    for (int j = 0; j < 4; ++j)
      bq[j] = ld8(Bc + (wn * 64 + j * 16 + lo) * 32 + quad * 8);
#pragma unroll
    for (int i = 0; i < 8; ++i)
#pragma unroll
      for (int j = 0; j < 4; ++j)
        acc[i][j] = MFMA16(af[i], bq[j], acc[i][j]);
    sc = (sc == 2) ? 0 : sc + 1;
    sp = (sp == 2) ? 0 : sp + 1;
  }

  // epilogue: two half-passes of 128 rows through LDS (stride SE)
  __syncthreads();
  const int orow = tid >> 4, ocol = (tid & 15) * 8;
#pragma unroll
  for (int hh = 0; hh < 2; ++hh) {
    if (wm == hh) {
#pragma unroll
      for (int i = 0; i < 8; ++i)
#pragma unroll
        for (int j = 0; j < 4; ++j)
#pragma unroll
          for (int r = 0; r < 4; ++r)
            smem[(i * 16 + quad * 4 + r) * SE + wn * 64 + j * 16 + lo] =
                f2b(acc[i][j][r]);
    }
    __syncthreads();
#pragma unroll
    for (int w = 0; w < 8; ++w) {
      int rl = orow + w * 16;
      int row = bm * 256 + hh * 128 + rl;
      u16x8 v = *(const u16x8*)(smem + rl * SE + ocol);
      if (SPLIT) {
        int proj = bn >> 3;
        int colp = (bn & 7) * 128 + ocol;
        *(u16x8*)(C + (u64)proj * BT * CC + (u64)row * CC + colp) = v;
      } else {
        u64 off = (u64)row * N + bn * 128 + ocol;
        if (MODE == 3) {
          u16x8 g = *(const u16x8*)(res + off);
          u16x8 o;
#pragma unroll
          for (int e = 0; e < 8; ++e) {
            float gg = b2f(g[e]);
            o[e] = f2b(gg * sigmoidf_(gg) * b2f(v[e]));
          }
          *(u16x8*)(C + off) = o;
        } else {
          *(u16x8*)(C + off) = v;
        }
      }
    }
    __syncthreads();
  }
}

// ---------------------------------------------------------------------------
// rmsnorm: fp32/bf16 in, bf16 out
// ---------------------------------------------------------------------------
template <int IN32>
__global__ __launch_bounds__(256) void rmsnorm_k(
    const void* __restrict__ xv, const u16* __restrict__ w, u16* __restrict__ out)
{
  __shared__ float red[4];
  const int row = blockIdx.x, tid = threadIdx.x;
  float v0, v1, v2, v3;
  if (IN32) {
    f32x4 raw = *(const f32x4*)((const float*)xv + (u64)row * CC + tid * 4);
    v0 = raw[0]; v1 = raw[1]; v2 = raw[2]; v3 = raw[3];
  } else {
    u16x4 raw = *(const u16x4*)((const u16*)xv + (u64)row * CC + tid * 4);
    v0 = b2f(raw[0]); v1 = b2f(raw[1]); v2 = b2f(raw[2]); v3 = b2f(raw[3]);
  }
  float s = v0 * v0 + v1 * v1 + v2 * v2 + v3 * v3;
#pragma unroll
  for (int m = 1; m < 64; m <<= 1) s += __shfl_xor(s, m, 64);
  if ((tid & 63) == 0) red[tid >> 6] = s;
  __syncthreads();
  float tot = red[0] + red[1] + red[2] + red[3];
  float r = rsqrtf(tot * (1.0f / CC) + 1e-6f);
  const u16* wr = w + tid * 4;
  u16x4 o;
  o[0] = f2b(v0 * r * b2f(wr[0]));
  o[1] = f2b(v1 * r * b2f(wr[1]));
  o[2] = f2b(v2 * r * b2f(wr[2]));
  o[3] = f2b(v3 * r * b2f(wr[3]));
  *(u16x4*)(out + (u64)row * CC + tid * 4) = o;
}

// per-head l2 normalize in place
__global__ __launch_bounds__(256) void l2norm_k(u16* __restrict__ q)
{
  const int row = blockIdx.x, tid = threadIdx.x;
  const int hh = tid >> 4, ss = tid & 15;
  u16* p = q + (u64)row * CC + hh * DD + ss * 4;
  u16x4 raw = *(const u16x4*)p;
  float v0 = b2f(raw[0]), v1 = b2f(raw[1]), v2 = b2f(raw[2]), v3 = b2f(raw[3]);
  float s = v0 * v0 + v1 * v1 + v2 * v2 + v3 * v3;
#pragma unroll
  for (int m = 1; m < 16; m <<= 1) s += __shfl_xor(s, m, 64);
  float sc = 1.0f / fmaxf(sqrtf(s), 1e-12f);
  u16x4 o;
  o[0] = f2b(v0 * sc); o[1] = f2b(v1 * sc);
  o[2] = f2b(v2 * sc); o[3] = f2b(v3 * sc);
  *(u16x4*)p = o;
}

// beta = sigmoid(xn @ bw^T + bb)
__global__ __launch_bounds__(256) void beta_k(
    const u16* __restrict__ xn, const u16* __restrict__ bw,
    const u16* __restrict__ bb, float* __restrict__ beta)
{
  const int row = blockIdx.x, tid = threadIdx.x;
  const int hh = tid >> 4, ss = tid & 15;
  const u16* xr = xn + (u64)row * CC + ss * 64;
  const u16* wr = bw + (u64)hh * CC + ss * 64;
  float s = 0.f;
#pragma unroll
  for (int j = 0; j < 8; ++j) {
    u16x8 a = *(const u16x8*)(xr + j * 8);
    u16x8 c = *(const u16x8*)(wr + j * 8);
#pragma unroll
    for (int e = 0; e < 8; ++e) s += b2f(a[e]) * b2f(c[e]);
  }
#pragma unroll
  for (int m = 1; m < 16; m <<= 1) s += __shfl_xor(s, m, 64);
  if (ss == 0) beta[(u64)row * HH + hh] = sigmoidf_(s + b2f(bb[hh]));
}

// ---------------------------------------------------------------------------
// chunk precompute (parallel over b,h,chunk)
// ---------------------------------------------------------------------------
__global__ __launch_bounds__(256) void chunk_pre(
    const u16* __restrict__ qn, const u16* __restrict__ kn,
    const u16* __restrict__ vn, const float* __restrict__ beta,
    u16* __restrict__ wneg, u16* __restrict__ u0m, u16* __restrict__ pm)
{
  __shared__ __align__(16) u16 Qc[64 * LS], Kc[64 * LS], Vc[64 * LS];
  __shared__ float Af[64 * 64];
  __shared__ float bet[64];
  const int tid = threadIdx.x;
  const int lane = tid & 63, wave = tid >> 6;
  const int lo = lane & 15, quad = lane >> 4;
  const int bc = blockIdx.x;
  const int bh = bc >> 5, c = bc & 31;
  const int b = bh >> 4, h = bh & 15;
  const u64 gbase = ((u64)(b * TT + c * LCH) * HH + h) * DD;
  const u64 cb = (u64)bc * 4096;

#pragma unroll
  for (int it = 0; it < 2; ++it) {
    int idx = tid + it * 256;
    int t = idx >> 3, seg = (idx & 7) * 8;
    u64 g = gbase + (u64)t * CC + seg;
    *(u16x8*)(Qc + t * LS + seg) = *(const u16x8*)(qn + g);
    *(u16x8*)(Kc + t * LS + seg) = *(const u16x8*)(kn + g);
    *(u16x8*)(Vc + t * LS + seg) = *(const u16x8*)(vn + g);
  }
  if (tid < 64) bet[tid] = beta[(u64)(b * TT + c * LCH + tid) * HH + h];
  __syncthreads();

  { // A = strict_tril(diag(beta) K K^T)
    const int wm = wave & 1, wn = wave >> 1;
    f32x4 aa[2][2] = {};
#pragma unroll
    for (int k0 = 0; k0 < 64; k0 += 32) {
      bf16x8 af[2], bq[2];
#pragma unroll
      for (int i = 0; i < 2; ++i) af[i] = ld8(Kc + (wm * 32 + i * 16 + lo) * LS + k0 + quad * 8);
#pragma unroll
      for (int j = 0; j < 2; ++j) bq[j] = ld8(Kc + (wn * 32 + j * 16 + lo) * LS + k0 + quad * 8);
#pragma unroll
      for (int i = 0; i < 2; ++i)
#pragma unroll
        for (int j = 0; j < 2; ++j) aa[i][j] = MFMA16(af[i], bq[j], aa[i][j]);
    }
#pragma unroll
    for (int i = 0; i < 2; ++i)
#pragma unroll
      for (int j = 0; j < 2; ++j)
#pragma unroll
        for (int r = 0; r < 4; ++r) {
          int t = wm * 32 + i * 16 + quad * 4 + r;
          int s = wn * 32 + j * 16 + lo;
          Af[t * 64 + s] = (s < t) ? bet[t] * aa[i][j][r] : 0.0f;
        }
  }
  __syncthreads();

  if (wave < 2) {
    // forward substitution of (I+A); lane = column d
    const u16* src = (wave == 0) ? Kc : Vc;
    u16* dst = (wave == 0) ? wneg : u0m;
    const float sgn = (wave == 0) ? -1.0f : 1.0f;
    const int d = lane;
    float hist[64];
#pragma unroll
    for (int t = 0; t < 64; ++t) {
      float a = bet[t] * b2f(src[t * LS + d]);
#pragma unroll
      for (int s = 0; s < t; ++s) a -= Af[t * 64 + s] * hist[s];
      hist[t] = a;
      dst[cb + (u64)t * 64 + d] = f2b(sgn * a);
    }
  } else {
    // P = strict_tril(Q K^T)
    const int w2 = wave - 2;
    f32x4 ap[2][4] = {};
#pragma unroll
    for (int k0 = 0; k0 < 64; k0 += 32) {
      bf16x8 af[2], bq[4];
#pragma unroll
      for (int i = 0; i < 2; ++i) af[i] = ld8(Qc + (w2 * 32 + i * 16 + lo) * LS + k0 + quad * 8);
#pragma unroll
      for (int j = 0; j < 4; ++j) bq[j] = ld8(Kc + (j * 16 + lo) * LS + k0 + quad * 8);
#pragma unroll
      for (int i = 0; i < 2; ++i)
#pragma unroll
        for (int j = 0; j < 4; ++j) ap[i][j] = MFMA16(af[i], bq[j], ap[i][j]);
    }
#pragma unroll
    for (int i = 0; i < 2; ++i)
#pragma unroll
      for (int j = 0; j < 4; ++j)
#pragma unroll
        for (int r = 0; r < 4; ++r) {
          int t = w2 * 32 + i * 16 + quad * 4 + r;
          int s = j * 16 + lo;
          pm[cb + (u64)t * 64 + s] = f2b((s < t) ? ap[i][j][r] : 0.0f);
        }
  }
}

// ---------------------------------------------------------------------------
// sequential chunk recurrence, split 4-way over dv; gate fused at the store
// ---------------------------------------------------------------------------
__global__ __launch_bounds__(256) void chunk_seq(
    const u16* __restrict__ qn, const u16* __restrict__ kn,
    const u16* __restrict__ wneg, const u16* __restrict__ u0m,
    const u16* __restrict__ pm, const u16* __restrict__ gate,
    u16* __restrict__ ob)
{
  __shared__ __align__(16) u16 Qs[64 * LS], KTs[64 * LS], Ws[64 * LS], Ps[64 * LS];
  __shared__ __align__(16) u16 U0q[64 * 16];
  __shared__ __align__(16) u16 Sq[16 * LS], UTq[16 * LS];
  const int tid = threadIdx.x;
  const int lane = tid & 63, wave = tid >> 6;
  const int lo = lane & 15, quad = lane >> 4;
  const int blk = blockIdx.x;
  const int bh = blk >> 2, q = blk & 3;
  const int b = bh >> 4, h = bh & 15;
  f32x4 Sacc = {};

  for (int i = tid; i < 16 * LS; i += 256) Sq[i] = 0;
  __syncthreads();

#pragma unroll 1
  for (int c = 0; c < NCH; ++c) {
    const u64 gbase = ((u64)(b * TT + c * LCH) * HH + h) * DD;
    const u64 cb = (u64)(bh * NCH + c) * 4096;
#pragma unroll
    for (int it = 0; it < 2; ++it) {
      int idx = tid + it * 256;
      int t = idx >> 3, seg = (idx & 7) * 8;
      u64 g = gbase + (u64)t * CC + seg;
      *(u16x8*)(Qs + t * LS + seg) = *(const u16x8*)(qn + g);
      u16x8 kv = *(const u16x8*)(kn + g);
#pragma unroll
      for (int jj = 0; jj < 8; ++jj) KTs[(seg + jj) * LS + t] = kv[jj];
      *(u16x8*)(Ws + t * LS + seg) = *(const u16x8*)(wneg + cb + t * 64 + seg);
      *(u16x8*)(Ps + t * LS + seg) = *(const u16x8*)(pm + cb + t * 64 + seg);
    }
    if (tid < 128) {
      int t = tid >> 1, half = (tid & 1) * 8;
      *(u16x8*)(U0q + t * 16 + half) =
          *(const u16x8*)(u0m + cb + t * 64 + q * 16 + half);
    }
    __syncthreads();

    // Phase A: Uq[t, dv16] = U0q + Wneg * Sq^T
    f32x4 au;
#pragma unroll
    for (int r = 0; r < 4; ++r)
      au[r] = b2f(U0q[(wave * 16 + quad * 4 + r) * 16 + lo]);
#pragma unroll
    for (int k0 = 0; k0 < 64; k0 += 32) {
      bf16x8 af = ld8(Ws + (wave * 16 + lo) * LS + k0 + quad * 8);
      bf16x8 bq = ld8(Sq + lo * LS + k0 + quad * 8);
      au = MFMA16(af, bq, au);
    }
#pragma unroll
    for (int r = 0; r < 4; ++r)
      UTq[lo * LS + wave * 16 + quad * 4 + r] = f2b(au[r]);
    __syncthreads();

    // Phase B: Oq = Q Sq^T + P Uq, gated store
    f32x4 ao = {};
#pragma unroll
    for (int k0 = 0; k0 < 64; k0 += 32) {
      bf16x8 af = ld8(Qs + (wave * 16 + lo) * LS + k0 + quad * 8);
      bf16x8 bq = ld8(Sq + lo * LS + k0 + quad * 8);
      ao = MFMA16(af, bq, ao);
    }
#pragma unroll
    for (int k0 = 0; k0 < 64; k0 += 32) {
      bf16x8 af = ld8(Ps + (wave * 16 + lo) * LS + k0 + quad * 8);
      bf16x8 bq = ld8(UTq + lo * LS + k0 + quad * 8);
      ao = MFMA16(af, bq, ao);
    }
#pragma unroll
    for (int r = 0; r < 4; ++r) {
      u64 gidx = gbase + (u64)(wave * 16 + quad * 4 + r) * CC + q * 16 + lo;
      float gg = b2f(gate[gidx]);
      ob[gidx] = f2b(sigmoidf_(gg) * ao[r]);
    }

    // S update: Sq += Uq^T K
#pragma unroll
    for (int k0 = 0; k0 < 64; k0 += 32) {
      bf16x8 af = ld8(UTq + lo * LS + k0 + quad * 8);
      bf16x8 bq = ld8(KTs + (wave * 16 + lo) * LS + k0 + quad * 8);
      Sacc = MFMA16(af, bq, Sacc);
    }
    __syncthreads();
#pragma unroll
    for (int r = 0; r < 4; ++r)
      Sq[(quad * 4 + r) * LS + wave * 16 + lo] = f2b(Sacc[r]);
    __syncthreads();
  }
}

extern "C" void kernel_launch(void* const* d_in, const int* in_sizes, int n_in,
                              void* d_out, int out_size, void* d_ws, size_t ws_size,
                              hipStream_t stream)
{
  (void)in_sizes; (void)n_in; (void)out_size; (void)ws_size;
  const float* x32 = (const float*)d_in[0];
  char* ws = (char*)d_ws;
  const u64 SZ = (u64)BT * CC * 2;            // 16 MiB
  const u64 MB = 1ull << 20;

  u16* xn1  = (u16*)(ws + 0 * SZ);
  u16* qb   = (u16*)(ws + 1 * SZ);            // qb,kb,vb,grw contiguous (QKVG dst)
  u16* kb   = (u16*)(ws + 2 * SZ);
  u16* vb   = (u16*)(ws + 3 * SZ);
  u16* grw  = (u16*)(ws + 4 * SZ);
  u16* wneg = (u16*)(ws + 5 * SZ);
  u16* u0m  = (u16*)(ws + 6 * SZ);
  u16* pmm  = (u16*)(ws + 7 * SZ);
  u16* obf  = (u16*)(ws + 8 * SZ);            // attn out; later aliased as xn2
  u16* x2   = (u16*)(ws + 9 * SZ);
  float* beta = (float*)(ws + 10 * SZ);       // 512 KiB
  char* CV  = ws + 10 * SZ + MB;              // canonical bf16 weights
  u16* qwc  = (u16*)(CV + 0 * MB);            // qwc..gwc contiguous [4096,1024]
  u16* kwc  = (u16*)(CV + 2 * MB);
  u16* vwc  = (u16*)(CV + 4 * MB);
  u16* gwc  = (u16*)(CV + 6 * MB);
  u16* owc  = (u16*)(CV + 8 * MB);
  u16* fgwc = (u16*)(CV + 10 * MB);
  u16* fuwc = (u16*)(CV + 18 * MB);
  u16* fdwc = (u16*)(CV + 26 * MB);
  u16* bwc  = (u16*)(CV + 34 * MB);
  u16* n1c  = (u16*)(CV + 34 * MB + 64 * 1024);
  u16* n2c  = (u16*)(CV + 34 * MB + 80 * 1024);
  u16* bbc  = (u16*)(CV + 34 * MB + 96 * 1024);
  u16* ffg  = (u16*)(ws + 0 * SZ);            // 64 MiB over xn1..vb (dead by then)
  u16* xn2  = obf;

  dim3 blk(256);
  dim3 g1(BT / 128, CC / 128);                // 128x128 kernels
  dim3 g2(BT / 256, FF / 128);                // 256x128 kernels (N=4096)

  CvtArgs ca;
  ca.d[0]  = { (const float*)d_in[5],  qwc,  (u32)(CC * CC), 0 };
  ca.d[1]  = { (const float*)d_in[6],  kwc,  (u32)(CC * CC), 0 };
  ca.d[2]  = { (const float*)d_in[7],  vwc,  (u32)(CC * CC), 0 };
  ca.d[3]  = { (const float*)d_in[10], gwc,  (u32)(CC * CC), 0 };
  ca.d[4]  = { (const float*)d_in[11], owc,  (u32)(CC * CC), 0 };
  ca.d[5]  = { (const float*)d_in[12], fgwc, (u32)(FF * CC), 0 };
  ca.d[6]  = { (const float*)d_in[13], fuwc, (u32)(FF * CC), 0 };
  ca.d[7]  = { (const float*)d_in[14], fdwc, (u32)(CC * FF), 0 };
  ca.d[8]  = { (const float*)d_in[8],  bwc,  (u32)(HH * CC), 0 };
  ca.d[9]  = { (const float*)d_in[3],  n1c,  (u32)CC, 0 };
  ca.d[10] = { (const float*)d_in[4],  n2c,  (u32)CC, 0 };
  ca.d[11] = { (const float*)d_in[9],  bbc,  (u32)HH, 0 };
  convert_k<<<dim3(2048, 12), blk, 0, stream>>>(ca);

  rmsnorm_k<1><<<BT, blk, 0, stream>>>(x32, n1c, xn1);
  // QKVG fused: one 8192x4096x1024 GEMM, de-interleaved into qb/kb/vb/grw
  gemm_bt2<0, 1><<<g2, blk, 0, stream>>>(xn1, qwc, qb, nullptr, BT, FF, CC);
  beta_k<<<BT, blk, 0, stream>>>(xn1, bwc, bbc, beta);
  l2norm_k<<<BT, blk, 0, stream>>>(qb);
  l2norm_k<<<BT, blk, 0, stream>>>(kb);
  chunk_pre<<<BQ * HH * NCH, blk, 0, stream>>>(qb, kb, vb, beta, wneg, u0m, pmm);
  chunk_seq<<<BQ * HH * 4, blk, 0, stream>>>(qb, kb, wneg, u0m, pmm, grw, obf);
  gemm_bt<1><<<g1, blk, 0, stream>>>(obf, owc, x2, x32, BT, CC, CC);
  rmsnorm_k<0><<<BT, blk, 0, stream>>>(x2, n2c, xn2);
  gemm_bt2<0, 0><<<g2, blk, 0, stream>>>(xn2, fgwc, ffg, nullptr, BT, FF, CC);
  gemm_bt2<3, 0><<<g2, blk, 0, stream>>>(xn2, fuwc, ffg, ffg, BT, FF, CC);
  gemm_bt<2><<<g1, blk, 0, stream>>>(ffg, fdwc, d_out, x2, BT, CC, FF);
}